// Round 7
// baseline (4440.291 us; speedup 1.0000x reference)
//
#include <hip/hip_runtime.h>
#include <hip/hip_bf16.h>

// Problem constants (hardcoded from setup_inputs):
// B=4, N=4096, C=256, h=8, d=32, H=W=L=16, M=512 (8x8x8), EPS=1e-5
#define SCALE_QK 0.17677669529663687f  // 32^-0.5

// ---------------------------------------------------------------------------
// prep: transpose weights (for coalesced GEMM reads) + zero ssq/sumv
// ---------------------------------------------------------------------------
__global__ __launch_bounds__(256) void prep_kernel(
    const float* __restrict__ pw, const float* __restrict__ kvw,
    const float* __restrict__ pjw,
    float* __restrict__ wtpw, float* __restrict__ wtkv, float* __restrict__ wtpj,
    float* __restrict__ ssq, float* __restrict__ sumv) {
  const int g = blockIdx.x * 256 + threadIdx.x;
  if (g < 65536) {
    const int c = g >> 8, o = g & 255;
    wtpw[g] = pw[o * 256 + c];
  } else if (g < 196608) {
    const int g2 = g - 65536;
    const int c = g2 >> 9, o = g2 & 511;
    wtkv[g2] = kvw[o * 256 + c];
  } else {
    const int g3 = g - 196608;
    const int c = g3 >> 8, o = g3 & 255;
    wtpj[g3] = pjw[o * 256 + c];
  }
  if (g < 512) ssq[g] = 0.0f;                      // 16-way spread x 32
  if (g >= 512 && g < 512 + 1024) sumv[g - 512] = 0.0f;
}

// ---------------------------------------------------------------------------
// depthwise conv3d (3x3x3, stride1, pad1) + BatchNorm (inference) -> qdw[B,N,C]
// ---------------------------------------------------------------------------
__global__ __launch_bounds__(256) void dwbn_kernel(
    const float* __restrict__ x, const float* __restrict__ w,
    const float* __restrict__ wb, const float* __restrict__ bg,
    const float* __restrict__ bb, const float* __restrict__ bm,
    const float* __restrict__ bv, float* __restrict__ outq) {
  const int blk = blockIdx.x;
  const int b = blk >> 12, n = blk & 4095;
  const int i0 = n >> 8, i1 = (n >> 4) & 15, i2 = n & 15;
  const int c = threadIdx.x;
  float acc = wb[c];
#pragma unroll
  for (int k0 = 0; k0 < 3; ++k0) {
    const int z = i0 + k0 - 1;
    if ((unsigned)z >= 16u) continue;
#pragma unroll
    for (int k1 = 0; k1 < 3; ++k1) {
      const int y = i1 + k1 - 1;
      if ((unsigned)y >= 16u) continue;
#pragma unroll
      for (int k2 = 0; k2 < 3; ++k2) {
        const int xx = i2 + k2 - 1;
        if ((unsigned)xx >= 16u) continue;
        acc = fmaf(w[c * 27 + (k0 * 3 + k1) * 3 + k2],
                   x[((b * 4096) + ((z * 16 + y) * 16 + xx)) * 256 + c], acc);
      }
    }
  }
  const float sc = bg[c] * rsqrtf(bv[c] + 1e-5f);
  outq[blk * 256 + c] = (acc - bm[c]) * sc + bb[c];
}

// ---------------------------------------------------------------------------
// strided depthwise conv3d (stride2) + LayerNorm over C -> xsln[B*M, C]
// ---------------------------------------------------------------------------
__global__ __launch_bounds__(256) void srln_kernel(
    const float* __restrict__ x, const float* __restrict__ w,
    const float* __restrict__ wb, const float* __restrict__ lg,
    const float* __restrict__ lb, float* __restrict__ outx) {
  const int blk = blockIdx.x;
  const int b = blk >> 9, m = blk & 511;
  const int o0 = m >> 6, o1 = (m >> 3) & 7, o2 = m & 7;
  const int c = threadIdx.x;
  float acc = wb[c];
#pragma unroll
  for (int k0 = 0; k0 < 3; ++k0) {
    const int z = o0 * 2 + k0 - 1;
    if ((unsigned)z >= 16u) continue;
#pragma unroll
    for (int k1 = 0; k1 < 3; ++k1) {
      const int y = o1 * 2 + k1 - 1;
      if ((unsigned)y >= 16u) continue;
#pragma unroll
      for (int k2 = 0; k2 < 3; ++k2) {
        const int xx = o2 * 2 + k2 - 1;
        if ((unsigned)xx >= 16u) continue;
        acc = fmaf(w[c * 27 + (k0 * 3 + k1) * 3 + k2],
                   x[((b * 4096) + ((z * 16 + y) * 16 + xx)) * 256 + c], acc);
      }
    }
  }
  __shared__ float r1[4], r2[4];
  float s1 = acc, s2 = acc * acc;
#pragma unroll
  for (int off = 32; off >= 1; off >>= 1) {
    s1 += __shfl_xor(s1, off);
    s2 += __shfl_xor(s2, off);
  }
  const int t = threadIdx.x;
  if ((t & 63) == 0) { r1[t >> 6] = s1; r2[t >> 6] = s2; }
  __syncthreads();
  const float mu = (r1[0] + r1[1] + r1[2] + r1[3]) * (1.0f / 256.0f);
  const float ms = (r2[0] + r2[1] + r2[2] + r2[3]) * (1.0f / 256.0f);
  const float rs = rsqrtf(ms - mu * mu + 1e-5f);
  outx[blk * 256 + c] = (acc - mu) * rs * lg[c] + lb[c];
}

// ---------------------------------------------------------------------------
// GEMM: Out[row][c0+cc] = sum_k A[row][k] * Wt[k][c0+cc] (+bias)
// MODE 1: deferred-instance-norm transform on A while staging.
// ---------------------------------------------------------------------------
template <int MODE>
__global__ __launch_bounds__(256) void gemm_kernel(
    const float* __restrict__ A, const float* __restrict__ Wt,
    const float* __restrict__ bias, float* __restrict__ Out, const int ldW,
    const float* __restrict__ sumv, const float* __restrict__ rstd) {
  __shared__ float a_t[32][68];
  __shared__ float w_s[32][260];
  const int t = threadIdx.x;
  const int r0 = blockIdx.x * 64;
  const int c0 = blockIdx.y * 256;
  const int rt = t & 15, ct = t >> 4;
  const int bidx = r0 >> 12;
  const float invM = 1.0f / 512.0f;
  float acc[4][16];
#pragma unroll
  for (int rr = 0; rr < 4; ++rr)
#pragma unroll
    for (int cc = 0; cc < 16; ++cc) acc[rr][cc] = 0.0f;

  for (int k0 = 0; k0 < 256; k0 += 32) {
    {  // stage A^T
      const int kk = t & 31;
      int rl = t >> 5;
#pragma unroll
      for (int p = 0; p < 8; ++p, rl += 8) {
        float v = A[(r0 + rl) * 256 + k0 + kk];
        if (MODE == 1) {
          const int kg = k0 + kk;
          v = (v - invM * sumv[bidx * 256 + kg]) * rstd[bidx * 8 + (kg >> 5)];
        }
        a_t[kk][rl] = v;
      }
    }
    {  // stage W
      const int cq = (t & 63) * 4;
      int kk = t >> 6;
#pragma unroll
      for (int p = 0; p < 8; ++p, kk += 4) {
        const float4 v = *(const float4*)&Wt[(k0 + kk) * ldW + c0 + cq];
        *(float4*)&w_s[kk][cq] = v;
      }
    }
    __syncthreads();
#pragma unroll
    for (int kk = 0; kk < 32; ++kk) {
      const float4 a4 = *(const float4*)&a_t[kk][rt * 4];
      const float av[4] = {a4.x, a4.y, a4.z, a4.w};
      float4 w4[4];
#pragma unroll
      for (int q = 0; q < 4; ++q) w4[q] = *(const float4*)&w_s[kk][ct * 16 + q * 4];
#pragma unroll
      for (int rr = 0; rr < 4; ++rr) {
#pragma unroll
        for (int q = 0; q < 4; ++q) {
          acc[rr][q * 4 + 0] = fmaf(av[rr], w4[q].x, acc[rr][q * 4 + 0]);
          acc[rr][q * 4 + 1] = fmaf(av[rr], w4[q].y, acc[rr][q * 4 + 1]);
          acc[rr][q * 4 + 2] = fmaf(av[rr], w4[q].z, acc[rr][q * 4 + 2]);
          acc[rr][q * 4 + 3] = fmaf(av[rr], w4[q].w, acc[rr][q * 4 + 3]);
        }
      }
    }
    __syncthreads();
  }
#pragma unroll
  for (int rr = 0; rr < 4; ++rr) {
    const int row = r0 + rt * 4 + rr;
#pragma unroll
    for (int q = 0; q < 4; ++q) {
      const int cc = c0 + ct * 16 + q * 4;
      float4 o;
      o.x = acc[rr][q * 4 + 0];
      o.y = acc[rr][q * 4 + 1];
      o.z = acc[rr][q * 4 + 2];
      o.w = acc[rr][q * 4 + 3];
      if (bias != nullptr) {
        o.x += bias[cc + 0]; o.y += bias[cc + 1];
        o.z += bias[cc + 2]; o.w += bias[cc + 3];
      }
      *(float4*)&Out[row * ldW + cc] = o;
    }
  }
}

// ---------------------------------------------------------------------------
// kt: K^T per batch -> ktb[b][k<256][m<512] (coalesced QK reads). LDS tiled.
// ---------------------------------------------------------------------------
__global__ __launch_bounds__(256) void kt_kernel(const float* __restrict__ kvb,
                                                 float* __restrict__ ktb) {
  __shared__ float tile[32][33];
  const int blk = blockIdx.x;  // b(4) x mt(16) x kt8(8)
  const int b = blk >> 7, mt = (blk >> 3) & 15, k8 = blk & 7;
  const int m0 = mt * 32, k0 = k8 * 32;
  const int t = threadIdx.x;
  {
    const int ml = t >> 3, kl = (t & 7) * 4;
    const float4 v = *(const float4*)&kvb[((b * 512 + m0 + ml) * 512) + k0 + kl];
    tile[ml][kl + 0] = v.x; tile[ml][kl + 1] = v.y;
    tile[ml][kl + 2] = v.z; tile[ml][kl + 3] = v.w;
  }
  __syncthreads();
  {
    const int kl = t >> 3, ml = (t & 7) * 4;
    float4 o;
    o.x = tile[ml + 0][kl]; o.y = tile[ml + 1][kl];
    o.z = tile[ml + 2][kl]; o.w = tile[ml + 3][kl];
    *(float4*)&ktb[((b * 256 + k0 + kl) * 512) + m0 + ml] = o;
  }
}

// ---------------------------------------------------------------------------
// sumv[b][c] = sum_m v[b][m][c]
// ---------------------------------------------------------------------------
__global__ __launch_bounds__(256) void sumv_kernel(const float* __restrict__ kvb,
                                                   float* __restrict__ sumv) {
  const int blk = blockIdx.x;
  const int b = blk >> 3, grp = blk & 7;
  const int c = threadIdx.x;
  float s = 0.0f;
  for (int mm = 0; mm < 64; ++mm) {
    const int m = grp * 64 + mm;
    s += kvb[((b * 512 + m) * 512) + 256 + c];
  }
  atomicAdd(&sumv[b * 256 + c], s);
}

__global__ void rstd_kernel(const float* __restrict__ ssq, float* __restrict__ rstd) {
  const int t = threadIdx.x;
  if (t < 32) {
    float s = 0.0f;
#pragma unroll
    for (int sp = 0; sp < 16; ++sp) s += ssq[sp * 32 + t];
    const float e2 = s * (1.0f / (4096.0f * 512.0f));
    const float invM = 1.0f / 512.0f;
    rstd[t] = rsqrtf(e2 - invM * invM + 1e-5f);
  }
}

// ---------------------------------------------------------------------------
// Fused attention v5: block = (b, 4 query rows). Distributed-m (wave w owns
// m in [w*128, +128) for all 4 rows x 8 heads; lane = 2 m), BUT K^T comes
// through LDS tiles (reusing P: 16 tiles of [16 k][512 m] = 32KB) so the
// FMA loop is LDS-latency -> no register spill (round-6 failure mode).
// j is compile-time via fully-unrolled j(8) x tt(2) tile loops.
// Flash 2-level softmax + PV in two head-groups: verbatim round-6 (verified).
// ---------------------------------------------------------------------------
__global__ __launch_bounds__(256, 4) void attn_kernel(
    const float* __restrict__ qb, const float* __restrict__ ktb,
    const float* __restrict__ kvb, const float* __restrict__ tw,
    const float* __restrict__ tb, float* __restrict__ ssq,
    float* __restrict__ out_un) {
  __shared__ float P[16 * 512];     // QK phase: K^T tile; PV phase: p/partials
  __shared__ float Qs[256 * 4];
  __shared__ float red[4][32][2];
  __shared__ float sqh[4][8];
  const int t = threadIdx.x;
  const int blk = blockIdx.x;
  const int b = blk >> 10;
  const int n0 = (blk & 1023) << 2;
  const int w = t >> 6, l = t & 63;

  {  // stage Q transposed [k][nn], scaled
    const int row = t >> 6, colq = t & 63;
    const float4 v = *(const float4*)&qb[((b * 4096 + n0 + row) * 256) + colq * 4];
    Qs[(colq * 4 + 0) * 4 + row] = v.x * SCALE_QK;
    Qs[(colq * 4 + 1) * 4 + row] = v.y * SCALE_QK;
    Qs[(colq * 4 + 2) * 4 + row] = v.z * SCALE_QK;
    Qs[(colq * 4 + 3) * 4 + row] = v.w * SCALE_QK;
  }

  // ---------------- QK via LDS K^T tiles; lane owns m = w*128 + l*2 + {0,1} -
  float raw[4][8][2];
#pragma unroll
  for (int nn = 0; nn < 4; ++nn)
#pragma unroll
    for (int j = 0; j < 8; ++j) raw[nn][j][0] = raw[nn][j][1] = 0.0f;

  const float* ktb_b = &ktb[(b * 256) << 9];
  const int moff = w * 128 + l * 2;
#pragma unroll
  for (int j = 0; j < 8; ++j) {
#pragma unroll
    for (int tt = 0; tt < 2; ++tt) {
      const int kb = j * 32 + tt * 16;
      __syncthreads();  // previous tile fully consumed (also covers Qs stage)
#pragma unroll
      for (int p = 0; p < 8; ++p) {
        const int off = p * 1024 + t * 4;
        *(float4*)&P[off] = *(const float4*)&ktb_b[(kb << 9) + off];
      }
      __syncthreads();
#pragma unroll
      for (int kt = 0; kt < 16; ++kt) {
        const float2 k2 = *(const float2*)&P[kt * 512 + moff];
        const float4 q4 = *(const float4*)&Qs[(kb + kt) * 4];  // broadcast
        raw[0][j][0] = fmaf(q4.x, k2.x, raw[0][j][0]);
        raw[0][j][1] = fmaf(q4.x, k2.y, raw[0][j][1]);
        raw[1][j][0] = fmaf(q4.y, k2.x, raw[1][j][0]);
        raw[1][j][1] = fmaf(q4.y, k2.y, raw[1][j][1]);
        raw[2][j][0] = fmaf(q4.z, k2.x, raw[2][j][0]);
        raw[2][j][1] = fmaf(q4.z, k2.y, raw[2][j][1]);
        raw[3][j][0] = fmaf(q4.w, k2.x, raw[3][j][0]);
        raw[3][j][1] = fmaf(q4.w, k2.y, raw[3][j][1]);
      }
    }
  }

  // ---------------- 8x8 head mix (+bias), lane-local, in place --------------
  {
    float Wr[8][8], tbr[8];
#pragma unroll
    for (int i = 0; i < 8; ++i) {
      tbr[i] = tb[i];
#pragma unroll
      for (int jj = 0; jj < 8; ++jj) Wr[i][jj] = tw[i * 8 + jj];
    }
#pragma unroll
    for (int nn = 0; nn < 4; ++nn) {
#pragma unroll
      for (int e = 0; e < 2; ++e) {
        float tmp[8];
#pragma unroll
        for (int i = 0; i < 8; ++i) tmp[i] = tbr[i];
#pragma unroll
        for (int jj = 0; jj < 8; ++jj) {
          const float r = raw[nn][jj][e];
#pragma unroll
          for (int i = 0; i < 8; ++i) tmp[i] = fmaf(Wr[i][jj], r, tmp[i]);
        }
#pragma unroll
        for (int i = 0; i < 8; ++i) raw[nn][i][e] = tmp[i];
      }
    }
  }

  // ---------------- flash softmax pass 1: wave-local max + expsum -----------
#pragma unroll
  for (int nn = 0; nn < 4; ++nn) {
#pragma unroll
    for (int i = 0; i < 8; ++i) {
      float mx = fmaxf(raw[nn][i][0], raw[nn][i][1]);
#pragma unroll
      for (int off = 32; off >= 1; off >>= 1) mx = fmaxf(mx, __shfl_xor(mx, off));
      const float e0 = __expf(raw[nn][i][0] - mx);
      const float e1 = __expf(raw[nn][i][1] - mx);
      raw[nn][i][0] = e0;
      raw[nn][i][1] = e1;
      float s = e0 + e1;
#pragma unroll
      for (int off = 32; off >= 1; off >>= 1) s += __shfl_xor(s, off);
      if (l == 0) { red[w][nn * 8 + i][0] = mx; red[w][nn * 8 + i][1] = s; }
    }
  }
  __syncthreads();   // also: all QK reads of P are done before PV overwrites

  // ---------------- pass 2: global combine, normalize in regs, sq -----------
  float sqh_l[8];
#pragma unroll
  for (int i = 0; i < 8; ++i) sqh_l[i] = 0.0f;
#pragma unroll
  for (int nn = 0; nn < 4; ++nn) {
#pragma unroll
    for (int i = 0; i < 8; ++i) {
      const int pr = nn * 8 + i;
      const float m0 = red[0][pr][0], m1 = red[1][pr][0];
      const float m2 = red[2][pr][0], m3 = red[3][pr][0];
      const float mx = fmaxf(fmaxf(m0, m1), fmaxf(m2, m3));
      const float S = red[0][pr][1] * __expf(m0 - mx) + red[1][pr][1] * __expf(m1 - mx) +
                      red[2][pr][1] * __expf(m2 - mx) + red[3][pr][1] * __expf(m3 - mx);
      const float mw = red[w][pr][0];
      const float scale = __expf(mw - mx) / S;
      const float p0 = raw[nn][i][0] * scale;
      const float p1 = raw[nn][i][1] * scale;
      raw[nn][i][0] = p0;
      raw[nn][i][1] = p1;
      sqh_l[i] = fmaf(p0, p0, sqh_l[i]);
      sqh_l[i] = fmaf(p1, p1, sqh_l[i]);
    }
  }
#pragma unroll
  for (int i = 0; i < 8; ++i) {
    float v = sqh_l[i];
#pragma unroll
    for (int off = 32; off >= 1; off >>= 1) v += __shfl_xor(v, off);
    if (l == 0) sqh[w][i] = v;
  }
  __syncthreads();
  if (t < 8) {
    const float s8 = sqh[0][t] + sqh[1][t] + sqh[2][t] + sqh[3][t];
    atomicAdd(&ssq[(blk & 15) * 32 + b * 8 + t], s8);
  }

  // ---------------- PV in two head-groups of 4 ----------------
  const int hd = l >> 4, half = (l >> 3) & 1, ds = l & 7;
  const int qsw = w * 32 + (l >> 1);  // quad index of lane's m-pair
  const int lo = (l & 1) * 2;         // float offset within quad
#pragma unroll
  for (int g = 0; g < 2; ++g) {
    // store p slices: row = il*4+nn, cols = lane's 2 m (XOR-quad swizzle ^il)
#pragma unroll
    for (int il = 0; il < 4; ++il) {
#pragma unroll
      for (int nn = 0; nn < 4; ++nn) {
        float2 pv;
        pv.x = raw[nn][g * 4 + il][0];
        pv.y = raw[nn][g * 4 + il][1];
        *(float2*)&P[(il * 4 + nn) * 512 + ((qsw ^ il) << 2) + lo] = pv;
      }
    }
    __syncthreads();

    // PV: lane (hd, half, ds); m-range = [w*128 + half*64, +64)
    float acc[4][4];
#pragma unroll
    for (int nn = 0; nn < 4; ++nn)
#pragma unroll
      for (int e = 0; e < 4; ++e) acc[nn][e] = 0.0f;
    const int mbase = w * 128 + half * 64;
    for (int mq = 0; mq < 16; ++mq) {
      const int m0 = mbase + mq * 4;
      float4 p4[4];
#pragma unroll
      for (int nn = 0; nn < 4; ++nn)
        p4[nn] = *(const float4*)&P[(hd * 4 + nn) * 512 + (((m0 >> 2) ^ hd) << 2)];
#pragma unroll
      for (int e = 0; e < 4; ++e) {
        const float4 v4 = *(const float4*)
            &kvb[((b * 512 + m0 + e) * 512) + 256 + (g * 4 + hd) * 32 + ds * 4];
#pragma unroll
        for (int nn = 0; nn < 4; ++nn) {
          const float p = (&p4[nn].x)[e];
          acc[nn][0] = fmaf(p, v4.x, acc[nn][0]);
          acc[nn][1] = fmaf(p, v4.y, acc[nn][1]);
          acc[nn][2] = fmaf(p, v4.z, acc[nn][2]);
          acc[nn][3] = fmaf(p, v4.w, acc[nn][3]);
        }
      }
    }
    __syncthreads();  // all P reads done before reuse as partial buffer

    const int pid = w * 2 + half;
#pragma unroll
    for (int nn = 0; nn < 4; ++nn) {
      float4 o;
      o.x = acc[nn][0]; o.y = acc[nn][1]; o.z = acc[nn][2]; o.w = acc[nn][3];
      *(float4*)&P[pid * 512 + (hd * 4 + nn) * 32 + ds * 4] = o;
    }
    __syncthreads();

    // reduce 8 partials, write this group's output columns
#pragma unroll
    for (int rep = 0; rep < 2; ++rep) {
      const int idx = rep * 256 + t;
      float s = 0.0f;
#pragma unroll
      for (int p2 = 0; p2 < 8; ++p2) s += P[p2 * 512 + idx];
      const int hd2 = idx >> 7, nn = (idx >> 5) & 3, dd = idx & 31;
      out_un[((b * 4096) + n0 + nn) * 256 + (g * 4 + hd2) * 32 + dd] = s;
    }
    __syncthreads();
  }
}

// ---------------------------------------------------------------------------
extern "C" void kernel_launch(void* const* d_in, const int* in_sizes, int n_in,
                              void* d_out, int out_size, void* d_ws, size_t ws_size,
                              hipStream_t stream) {
  const float* x   = (const float*)d_in[0];
  const float* qdww= (const float*)d_in[1];
  const float* qdwb= (const float*)d_in[2];
  const float* bng = (const float*)d_in[3];
  const float* bnb = (const float*)d_in[4];
  const float* bnm = (const float*)d_in[5];
  const float* bnv = (const float*)d_in[6];
  const float* pw  = (const float*)d_in[7];
  const float* pwb = (const float*)d_in[8];
  const float* srw = (const float*)d_in[9];
  const float* srb = (const float*)d_in[10];
  const float* lng = (const float*)d_in[11];
  const float* lnb = (const float*)d_in[12];
  const float* kvw = (const float*)d_in[13];
  const float* tw  = (const float*)d_in[14];
  const float* tb  = (const float*)d_in[15];
  const float* pjw = (const float*)d_in[16];
  const float* pjb = (const float*)d_in[17];
  float* out = (float*)d_out;
  float* ws = (float*)d_ws;

  float* qdw   = ws + 0;          // 4,194,304
  float* qbuf  = ws + 4194304;    // 4,194,304
  float* xsln  = ws + 8388608;    //   524,288
  float* kvb   = ws + 8912896;    // 1,048,576
  float* ktb   = ws + 9961472;    //   524,288
  float* wtpw  = ws + 10485760;   //    65,536
  float* wtkv  = ws + 10551296;   //   131,072
  float* wtpj  = ws + 10682368;   //    65,536
  float* sumvp = ws + 10747904;   //     1,024
  float* ssqp  = ws + 10748928;   //       512
  float* rstdp = ws + 10749440;   //        32

  prep_kernel<<<1024, 256, 0, stream>>>(pw, kvw, pjw, wtpw, wtkv, wtpj, ssqp, sumvp);
  dwbn_kernel<<<16384, 256, 0, stream>>>(x, qdww, qdwb, bng, bnb, bnm, bnv, qdw);
  gemm_kernel<0><<<dim3(256, 1), 256, 0, stream>>>(qdw, wtpw, pwb, qbuf, 256, nullptr, nullptr);
  srln_kernel<<<2048, 256, 0, stream>>>(x, srw, srb, lng, lnb, xsln);
  gemm_kernel<0><<<dim3(32, 2), 256, 0, stream>>>(xsln, wtkv, nullptr, kvb, 512, nullptr, nullptr);
  kt_kernel<<<512, 256, 0, stream>>>(kvb, ktb);
  sumv_kernel<<<32, 256, 0, stream>>>(kvb, sumvp);
  attn_kernel<<<4096, 256, 0, stream>>>(qbuf, ktb, kvb, tw, tb, ssqp, out);
  rstd_kernel<<<1, 64, 0, stream>>>(ssqp, rstdp);
  gemm_kernel<1><<<dim3(256, 1), 256, 0, stream>>>(out, wtpj, pjb, out, 256, sumvp, rstdp);
}

// Round 8
// 552.706 us; speedup vs baseline: 8.0337x; 8.0337x over previous
//
#include <hip/hip_runtime.h>
#include <hip/hip_bf16.h>

// Problem constants (hardcoded from setup_inputs):
// B=4, N=4096, C=256, h=8, d=32, H=W=L=16, M=512 (8x8x8), EPS=1e-5
#define SCALE_QK 0.17677669529663687f  // 32^-0.5

// ---------------------------------------------------------------------------
// prep: transpose weights (for coalesced GEMM reads) + zero ssq/sumv
// ---------------------------------------------------------------------------
__global__ __launch_bounds__(256) void prep_kernel(
    const float* __restrict__ pw, const float* __restrict__ kvw,
    const float* __restrict__ pjw,
    float* __restrict__ wtpw, float* __restrict__ wtkv, float* __restrict__ wtpj,
    float* __restrict__ ssq, float* __restrict__ sumv) {
  const int g = blockIdx.x * 256 + threadIdx.x;
  if (g < 65536) {
    const int c = g >> 8, o = g & 255;
    wtpw[g] = pw[o * 256 + c];
  } else if (g < 196608) {
    const int g2 = g - 65536;
    const int c = g2 >> 9, o = g2 & 511;
    wtkv[g2] = kvw[o * 256 + c];
  } else {
    const int g3 = g - 196608;
    const int c = g3 >> 8, o = g3 & 255;
    wtpj[g3] = pjw[o * 256 + c];
  }
  if (g < 512) ssq[g] = 0.0f;                      // 16-way spread x 32
  if (g >= 512 && g < 512 + 1024) sumv[g - 512] = 0.0f;
}

// ---------------------------------------------------------------------------
// depthwise conv3d (3x3x3, stride1, pad1) + BatchNorm (inference) -> qdw[B,N,C]
// ---------------------------------------------------------------------------
__global__ __launch_bounds__(256) void dwbn_kernel(
    const float* __restrict__ x, const float* __restrict__ w,
    const float* __restrict__ wb, const float* __restrict__ bg,
    const float* __restrict__ bb, const float* __restrict__ bm,
    const float* __restrict__ bv, float* __restrict__ outq) {
  const int blk = blockIdx.x;
  const int b = blk >> 12, n = blk & 4095;
  const int i0 = n >> 8, i1 = (n >> 4) & 15, i2 = n & 15;
  const int c = threadIdx.x;
  float acc = wb[c];
#pragma unroll
  for (int k0 = 0; k0 < 3; ++k0) {
    const int z = i0 + k0 - 1;
    if ((unsigned)z >= 16u) continue;
#pragma unroll
    for (int k1 = 0; k1 < 3; ++k1) {
      const int y = i1 + k1 - 1;
      if ((unsigned)y >= 16u) continue;
#pragma unroll
      for (int k2 = 0; k2 < 3; ++k2) {
        const int xx = i2 + k2 - 1;
        if ((unsigned)xx >= 16u) continue;
        acc = fmaf(w[c * 27 + (k0 * 3 + k1) * 3 + k2],
                   x[((b * 4096) + ((z * 16 + y) * 16 + xx)) * 256 + c], acc);
      }
    }
  }
  const float sc = bg[c] * rsqrtf(bv[c] + 1e-5f);
  outq[blk * 256 + c] = (acc - bm[c]) * sc + bb[c];
}

// ---------------------------------------------------------------------------
// strided depthwise conv3d (stride2) + LayerNorm over C -> xsln[B*M, C]
// ---------------------------------------------------------------------------
__global__ __launch_bounds__(256) void srln_kernel(
    const float* __restrict__ x, const float* __restrict__ w,
    const float* __restrict__ wb, const float* __restrict__ lg,
    const float* __restrict__ lb, float* __restrict__ outx) {
  const int blk = blockIdx.x;
  const int b = blk >> 9, m = blk & 511;
  const int o0 = m >> 6, o1 = (m >> 3) & 7, o2 = m & 7;
  const int c = threadIdx.x;
  float acc = wb[c];
#pragma unroll
  for (int k0 = 0; k0 < 3; ++k0) {
    const int z = o0 * 2 + k0 - 1;
    if ((unsigned)z >= 16u) continue;
#pragma unroll
    for (int k1 = 0; k1 < 3; ++k1) {
      const int y = o1 * 2 + k1 - 1;
      if ((unsigned)y >= 16u) continue;
#pragma unroll
      for (int k2 = 0; k2 < 3; ++k2) {
        const int xx = o2 * 2 + k2 - 1;
        if ((unsigned)xx >= 16u) continue;
        acc = fmaf(w[c * 27 + (k0 * 3 + k1) * 3 + k2],
                   x[((b * 4096) + ((z * 16 + y) * 16 + xx)) * 256 + c], acc);
      }
    }
  }
  __shared__ float r1[4], r2[4];
  float s1 = acc, s2 = acc * acc;
#pragma unroll
  for (int off = 32; off >= 1; off >>= 1) {
    s1 += __shfl_xor(s1, off);
    s2 += __shfl_xor(s2, off);
  }
  const int t = threadIdx.x;
  if ((t & 63) == 0) { r1[t >> 6] = s1; r2[t >> 6] = s2; }
  __syncthreads();
  const float mu = (r1[0] + r1[1] + r1[2] + r1[3]) * (1.0f / 256.0f);
  const float ms = (r2[0] + r2[1] + r2[2] + r2[3]) * (1.0f / 256.0f);
  const float rs = rsqrtf(ms - mu * mu + 1e-5f);
  outx[blk * 256 + c] = (acc - mu) * rs * lg[c] + lb[c];
}

// ---------------------------------------------------------------------------
// GEMM: Out[row][c0+cc] = sum_k A[row][k] * Wt[k][c0+cc] (+bias)
// MODE 1: deferred-instance-norm transform on A while staging.
// ---------------------------------------------------------------------------
template <int MODE>
__global__ __launch_bounds__(256) void gemm_kernel(
    const float* __restrict__ A, const float* __restrict__ Wt,
    const float* __restrict__ bias, float* __restrict__ Out, const int ldW,
    const float* __restrict__ sumv, const float* __restrict__ rstd) {
  __shared__ float a_t[32][68];
  __shared__ float w_s[32][260];
  const int t = threadIdx.x;
  const int r0 = blockIdx.x * 64;
  const int c0 = blockIdx.y * 256;
  const int rt = t & 15, ct = t >> 4;
  const int bidx = r0 >> 12;
  const float invM = 1.0f / 512.0f;
  float acc[4][16];
#pragma unroll
  for (int rr = 0; rr < 4; ++rr)
#pragma unroll
    for (int cc = 0; cc < 16; ++cc) acc[rr][cc] = 0.0f;

  for (int k0 = 0; k0 < 256; k0 += 32) {
    {  // stage A^T
      const int kk = t & 31;
      int rl = t >> 5;
#pragma unroll
      for (int p = 0; p < 8; ++p, rl += 8) {
        float v = A[(r0 + rl) * 256 + k0 + kk];
        if (MODE == 1) {
          const int kg = k0 + kk;
          v = (v - invM * sumv[bidx * 256 + kg]) * rstd[bidx * 8 + (kg >> 5)];
        }
        a_t[kk][rl] = v;
      }
    }
    {  // stage W
      const int cq = (t & 63) * 4;
      int kk = t >> 6;
#pragma unroll
      for (int p = 0; p < 8; ++p, kk += 4) {
        const float4 v = *(const float4*)&Wt[(k0 + kk) * ldW + c0 + cq];
        *(float4*)&w_s[kk][cq] = v;
      }
    }
    __syncthreads();
#pragma unroll
    for (int kk = 0; kk < 32; ++kk) {
      const float4 a4 = *(const float4*)&a_t[kk][rt * 4];
      const float av[4] = {a4.x, a4.y, a4.z, a4.w};
      float4 w4[4];
#pragma unroll
      for (int q = 0; q < 4; ++q) w4[q] = *(const float4*)&w_s[kk][ct * 16 + q * 4];
#pragma unroll
      for (int rr = 0; rr < 4; ++rr) {
#pragma unroll
        for (int q = 0; q < 4; ++q) {
          acc[rr][q * 4 + 0] = fmaf(av[rr], w4[q].x, acc[rr][q * 4 + 0]);
          acc[rr][q * 4 + 1] = fmaf(av[rr], w4[q].y, acc[rr][q * 4 + 1]);
          acc[rr][q * 4 + 2] = fmaf(av[rr], w4[q].z, acc[rr][q * 4 + 2]);
          acc[rr][q * 4 + 3] = fmaf(av[rr], w4[q].w, acc[rr][q * 4 + 3]);
        }
      }
    }
    __syncthreads();
  }
#pragma unroll
  for (int rr = 0; rr < 4; ++rr) {
    const int row = r0 + rt * 4 + rr;
#pragma unroll
    for (int q = 0; q < 4; ++q) {
      const int cc = c0 + ct * 16 + q * 4;
      float4 o;
      o.x = acc[rr][q * 4 + 0];
      o.y = acc[rr][q * 4 + 1];
      o.z = acc[rr][q * 4 + 2];
      o.w = acc[rr][q * 4 + 3];
      if (bias != nullptr) {
        o.x += bias[cc + 0]; o.y += bias[cc + 1];
        o.z += bias[cc + 2]; o.w += bias[cc + 3];
      }
      *(float4*)&Out[row * ldW + cc] = o;
    }
  }
}

// ---------------------------------------------------------------------------
// kt: K^T per batch -> ktb[b][k<256][m<512] (coalesced QK reads). LDS tiled.
// ---------------------------------------------------------------------------
__global__ __launch_bounds__(256) void kt_kernel(const float* __restrict__ kvb,
                                                 float* __restrict__ ktb) {
  __shared__ float tile[32][33];
  const int blk = blockIdx.x;  // b(4) x mt(16) x kt8(8)
  const int b = blk >> 7, mt = (blk >> 3) & 15, k8 = blk & 7;
  const int m0 = mt * 32, k0 = k8 * 32;
  const int t = threadIdx.x;
  {
    const int ml = t >> 3, kl = (t & 7) * 4;
    const float4 v = *(const float4*)&kvb[((b * 512 + m0 + ml) * 512) + k0 + kl];
    tile[ml][kl + 0] = v.x; tile[ml][kl + 1] = v.y;
    tile[ml][kl + 2] = v.z; tile[ml][kl + 3] = v.w;
  }
  __syncthreads();
  {
    const int kl = t >> 3, ml = (t & 7) * 4;
    float4 o;
    o.x = tile[ml + 0][kl]; o.y = tile[ml + 1][kl];
    o.z = tile[ml + 2][kl]; o.w = tile[ml + 3][kl];
    *(float4*)&ktb[((b * 256 + k0 + kl) * 512) + m0 + ml] = o;
  }
}

// ---------------------------------------------------------------------------
// sumv[b][c] = sum_m v[b][m][c]
// ---------------------------------------------------------------------------
__global__ __launch_bounds__(256) void sumv_kernel(const float* __restrict__ kvb,
                                                   float* __restrict__ sumv) {
  const int blk = blockIdx.x;
  const int b = blk >> 3, grp = blk & 7;
  const int c = threadIdx.x;
  float s = 0.0f;
  for (int mm = 0; mm < 64; ++mm) {
    const int m = grp * 64 + mm;
    s += kvb[((b * 512 + m) * 512) + 256 + c];
  }
  atomicAdd(&sumv[b * 256 + c], s);
}

__global__ void rstd_kernel(const float* __restrict__ ssq, float* __restrict__ rstd) {
  const int t = threadIdx.x;
  if (t < 32) {
    float s = 0.0f;
#pragma unroll
    for (int sp = 0; sp < 16; ++sp) s += ssq[sp * 32 + t];
    const float e2 = s * (1.0f / (4096.0f * 512.0f));
    const float invM = 1.0f / 512.0f;
    rstd[t] = rsqrtf(e2 - invM * invM + 1e-5f);
  }
}

// ---------------------------------------------------------------------------
// Fused attention v6: block = (b, 4 q-rows), 512 threads = 8 waves.
// Wave = head: QK reads K^T rows ONCE per block (coalesced float2, lane=2m
// per 128-m group), acc in regs. Scores -> 64KB LDS (2-way-free b64).
// Mix: wave = (q-row, 4-head group), Wr[4][8]; tb dropped (softmax-invariant).
// Softmax in regs + shfl. PV: wave = head, V read once, shfl reduce, direct
// coalesced out write. ALL barriers at top level -- no barrier-containing
// loop indexes any register array (round-6/7 scratch-spill trigger).
// ---------------------------------------------------------------------------
__global__ __launch_bounds__(512, 4) void attn_kernel(
    const float* __restrict__ qb, const float* __restrict__ ktb,
    const float* __restrict__ kvb, const float* __restrict__ tw,
    float* __restrict__ ssq, float* __restrict__ out_un) {
  __shared__ float P[32 * 512];   // scores then p: row = nn*8 + head
  __shared__ float Qs[256 * 4];   // Qs[k*4 + row], scaled
  __shared__ float sq_lds[4][8];
  const int t = threadIdx.x;
  const int blk = blockIdx.x;
  const int b = blk >> 10;
  const int n0 = (blk & 1023) << 2;
  const int w = t >> 6, l = t & 63;

  if (t < 256) {  // stage Q transposed [k][row], scaled
    const int row = t >> 6, colq = t & 63;
    const float4 v = *(const float4*)&qb[((b * 4096 + n0 + row) * 256) + colq * 4];
    Qs[(colq * 4 + 0) * 4 + row] = v.x * SCALE_QK;
    Qs[(colq * 4 + 1) * 4 + row] = v.y * SCALE_QK;
    Qs[(colq * 4 + 2) * 4 + row] = v.z * SCALE_QK;
    Qs[(colq * 4 + 3) * 4 + row] = v.w * SCALE_QK;
  }
  __syncthreads();

  // ---------------- QK: wave w = head; lane m = l*2+{0,1} + e*128 -----------
  float acc[4][8];  // [q-row nn][e*2+s]
#pragma unroll
  for (int nn = 0; nn < 4; ++nn)
#pragma unroll
    for (int e = 0; e < 8; ++e) acc[nn][e] = 0.0f;
  {
    const float* ktr = &ktb[(size_t)((b * 256 + w * 32) << 9)];
    const int m2 = l * 2;
#pragma unroll 8
    for (int k = 0; k < 32; ++k) {
      const float4 q4 = *(const float4*)&Qs[(w * 32 + k) * 4];  // broadcast
      const float2 c0 = *(const float2*)&ktr[(k << 9) + m2];
      const float2 c1 = *(const float2*)&ktr[(k << 9) + 128 + m2];
      const float2 c2 = *(const float2*)&ktr[(k << 9) + 256 + m2];
      const float2 c3 = *(const float2*)&ktr[(k << 9) + 384 + m2];
      acc[0][0] = fmaf(q4.x, c0.x, acc[0][0]); acc[0][1] = fmaf(q4.x, c0.y, acc[0][1]);
      acc[0][2] = fmaf(q4.x, c1.x, acc[0][2]); acc[0][3] = fmaf(q4.x, c1.y, acc[0][3]);
      acc[0][4] = fmaf(q4.x, c2.x, acc[0][4]); acc[0][5] = fmaf(q4.x, c2.y, acc[0][5]);
      acc[0][6] = fmaf(q4.x, c3.x, acc[0][6]); acc[0][7] = fmaf(q4.x, c3.y, acc[0][7]);
      acc[1][0] = fmaf(q4.y, c0.x, acc[1][0]); acc[1][1] = fmaf(q4.y, c0.y, acc[1][1]);
      acc[1][2] = fmaf(q4.y, c1.x, acc[1][2]); acc[1][3] = fmaf(q4.y, c1.y, acc[1][3]);
      acc[1][4] = fmaf(q4.y, c2.x, acc[1][4]); acc[1][5] = fmaf(q4.y, c2.y, acc[1][5]);
      acc[1][6] = fmaf(q4.y, c3.x, acc[1][6]); acc[1][7] = fmaf(q4.y, c3.y, acc[1][7]);
      acc[2][0] = fmaf(q4.z, c0.x, acc[2][0]); acc[2][1] = fmaf(q4.z, c0.y, acc[2][1]);
      acc[2][2] = fmaf(q4.z, c1.x, acc[2][2]); acc[2][3] = fmaf(q4.z, c1.y, acc[2][3]);
      acc[2][4] = fmaf(q4.z, c2.x, acc[2][4]); acc[2][5] = fmaf(q4.z, c2.y, acc[2][5]);
      acc[2][6] = fmaf(q4.z, c3.x, acc[2][6]); acc[2][7] = fmaf(q4.z, c3.y, acc[2][7]);
      acc[3][0] = fmaf(q4.w, c0.x, acc[3][0]); acc[3][1] = fmaf(q4.w, c0.y, acc[3][1]);
      acc[3][2] = fmaf(q4.w, c1.x, acc[3][2]); acc[3][3] = fmaf(q4.w, c1.y, acc[3][3]);
      acc[3][4] = fmaf(q4.w, c2.x, acc[3][4]); acc[3][5] = fmaf(q4.w, c2.y, acc[3][5]);
      acc[3][6] = fmaf(q4.w, c3.x, acc[3][6]); acc[3][7] = fmaf(q4.w, c3.y, acc[3][7]);
    }
  }
  // write raw scores to LDS: row = nn*8 + w
#pragma unroll
  for (int nn = 0; nn < 4; ++nn) {
#pragma unroll
    for (int e = 0; e < 4; ++e) {
      float2 s2;
      s2.x = acc[nn][e * 2 + 0];
      s2.y = acc[nn][e * 2 + 1];
      *(float2*)&P[(nn * 8 + w) * 512 + e * 128 + l * 2] = s2;
    }
  }
  __syncthreads();

  // ---------------- mix: wave = (q-row nn=w&3, head-group g=w>>2) -----------
  const int nnw = w & 3, gw = w >> 2;
  float mixed[4][8];  // [il][e*2+s]
  {
    float Wr[4][8];
#pragma unroll
    for (int il = 0; il < 4; ++il)
#pragma unroll
      for (int jj = 0; jj < 8; ++jj) Wr[il][jj] = tw[(gw * 4 + il) * 8 + jj];
#pragma unroll
    for (int il = 0; il < 4; ++il)
#pragma unroll
      for (int e = 0; e < 8; ++e) mixed[il][e] = 0.0f;  // tb dropped: softmax-invariant
#pragma unroll
    for (int jj = 0; jj < 8; ++jj) {
#pragma unroll
      for (int e = 0; e < 4; ++e) {
        const float2 r2 = *(const float2*)&P[(nnw * 8 + jj) * 512 + e * 128 + l * 2];
#pragma unroll
        for (int il = 0; il < 4; ++il) {
          mixed[il][e * 2 + 0] = fmaf(Wr[il][jj], r2.x, mixed[il][e * 2 + 0]);
          mixed[il][e * 2 + 1] = fmaf(Wr[il][jj], r2.y, mixed[il][e * 2 + 1]);
        }
      }
    }
  }
  __syncthreads();  // all mix reads done before p overwrites scores

  // ---------------- softmax per (nnw, head gw*4+il) in regs ----------------
#pragma unroll
  for (int il = 0; il < 4; ++il) {
    float mx = mixed[il][0];
#pragma unroll
    for (int e = 1; e < 8; ++e) mx = fmaxf(mx, mixed[il][e]);
#pragma unroll
    for (int off = 32; off >= 1; off >>= 1) mx = fmaxf(mx, __shfl_xor(mx, off));
    float s = 0.0f;
#pragma unroll
    for (int e = 0; e < 8; ++e) {
      const float ev = __expf(mixed[il][e] - mx);
      mixed[il][e] = ev;
      s += ev;
    }
#pragma unroll
    for (int off = 32; off >= 1; off >>= 1) s += __shfl_xor(s, off);
    const float rinv = 1.0f / s;
    float sq = 0.0f;
#pragma unroll
    for (int e = 0; e < 4; ++e) {
      float2 pv;
      pv.x = mixed[il][e * 2 + 0] * rinv;
      pv.y = mixed[il][e * 2 + 1] * rinv;
      sq = fmaf(pv.x, pv.x, sq);
      sq = fmaf(pv.y, pv.y, sq);
      *(float2*)&P[(nnw * 8 + gw * 4 + il) * 512 + e * 128 + l * 2] = pv;
    }
#pragma unroll
    for (int off = 32; off >= 1; off >>= 1) sq += __shfl_xor(sq, off);
    if (l == 0) sq_lds[nnw][gw * 4 + il] = sq;
  }
  __syncthreads();

  if (t < 8) {
    const float s8 = sq_lds[0][t] + sq_lds[1][t] + sq_lds[2][t] + sq_lds[3][t];
    atomicAdd(&ssq[(blk & 15) * 32 + b * 8 + t], s8);
  }

  // ---------------- PV: wave w = head; lane (mgrp=l>>3, d=l&7) --------------
  {
    float av[4][4];  // [nn][d-comp]
#pragma unroll
    for (int nn = 0; nn < 4; ++nn)
#pragma unroll
      for (int e = 0; e < 4; ++e) av[nn][e] = 0.0f;
    const int mbase = (l >> 3) * 64;
    const int vcol = 256 + w * 32 + (l & 7) * 4;
#pragma unroll 4
    for (int mq = 0; mq < 16; ++mq) {
      const int m0 = mbase + mq * 4;
      float4 p4[4];
#pragma unroll
      for (int nn = 0; nn < 4; ++nn)
        p4[nn] = *(const float4*)&P[(nn * 8 + w) * 512 + m0];
#pragma unroll
      for (int e = 0; e < 4; ++e) {
        const float4 v4 = *(const float4*)&kvb[((b * 512 + m0 + e) * 512) + vcol];
#pragma unroll
        for (int nn = 0; nn < 4; ++nn) {
          const float p = (&p4[nn].x)[e];
          av[nn][0] = fmaf(p, v4.x, av[nn][0]);
          av[nn][1] = fmaf(p, v4.y, av[nn][1]);
          av[nn][2] = fmaf(p, v4.z, av[nn][2]);
          av[nn][3] = fmaf(p, v4.w, av[nn][3]);
        }
      }
    }
    // reduce across the 8 m-groups (lanes differing in bits 3..5)
#pragma unroll
    for (int nn = 0; nn < 4; ++nn) {
#pragma unroll
      for (int e = 0; e < 4; ++e) {
        float v = av[nn][e];
        v += __shfl_xor(v, 8);
        v += __shfl_xor(v, 16);
        v += __shfl_xor(v, 32);
        av[nn][e] = v;
      }
    }
    if (l < 8) {
#pragma unroll
      for (int nn = 0; nn < 4; ++nn) {
        float4 o;
        o.x = av[nn][0]; o.y = av[nn][1]; o.z = av[nn][2]; o.w = av[nn][3];
        *(float4*)&out_un[((b * 4096) + n0 + nn) * 256 + w * 32 + l * 4] = o;
      }
    }
  }
}

// ---------------------------------------------------------------------------
extern "C" void kernel_launch(void* const* d_in, const int* in_sizes, int n_in,
                              void* d_out, int out_size, void* d_ws, size_t ws_size,
                              hipStream_t stream) {
  const float* x   = (const float*)d_in[0];
  const float* qdww= (const float*)d_in[1];
  const float* qdwb= (const float*)d_in[2];
  const float* bng = (const float*)d_in[3];
  const float* bnb = (const float*)d_in[4];
  const float* bnm = (const float*)d_in[5];
  const float* bnv = (const float*)d_in[6];
  const float* pw  = (const float*)d_in[7];
  const float* pwb = (const float*)d_in[8];
  const float* srw = (const float*)d_in[9];
  const float* srb = (const float*)d_in[10];
  const float* lng = (const float*)d_in[11];
  const float* lnb = (const float*)d_in[12];
  const float* kvw = (const float*)d_in[13];
  const float* tw  = (const float*)d_in[14];
  // d_in[15] = trans_b: softmax-invariant, unused
  const float* pjw = (const float*)d_in[16];
  const float* pjb = (const float*)d_in[17];
  float* out = (float*)d_out;
  float* ws = (float*)d_ws;

  float* qdw   = ws + 0;          // 4,194,304
  float* qbuf  = ws + 4194304;    // 4,194,304
  float* xsln  = ws + 8388608;    //   524,288
  float* kvb   = ws + 8912896;    // 1,048,576
  float* ktb   = ws + 9961472;    //   524,288
  float* wtpw  = ws + 10485760;   //    65,536
  float* wtkv  = ws + 10551296;   //   131,072
  float* wtpj  = ws + 10682368;   //    65,536
  float* sumvp = ws + 10747904;   //     1,024
  float* ssqp  = ws + 10748928;   //       512
  float* rstdp = ws + 10749440;   //        32

  prep_kernel<<<1024, 256, 0, stream>>>(pw, kvw, pjw, wtpw, wtkv, wtpj, ssqp, sumvp);
  dwbn_kernel<<<16384, 256, 0, stream>>>(x, qdww, qdwb, bng, bnb, bnm, bnv, qdw);
  gemm_kernel<0><<<dim3(256, 1), 256, 0, stream>>>(qdw, wtpw, pwb, qbuf, 256, nullptr, nullptr);
  srln_kernel<<<2048, 256, 0, stream>>>(x, srw, srb, lng, lnb, xsln);
  gemm_kernel<0><<<dim3(32, 2), 256, 0, stream>>>(xsln, wtkv, nullptr, kvb, 512, nullptr, nullptr);
  kt_kernel<<<512, 256, 0, stream>>>(kvb, ktb);
  sumv_kernel<<<32, 256, 0, stream>>>(kvb, sumvp);
  attn_kernel<<<4096, 512, 0, stream>>>(qbuf, ktb, kvb, tw, ssqp, out);
  rstd_kernel<<<1, 64, 0, stream>>>(ssqp, rstdp);
  gemm_kernel<1><<<dim3(256, 1), 256, 0, stream>>>(out, wtpj, pjb, out, 256, sumvp, rstdp);
}

// Round 9
// 504.646 us; speedup vs baseline: 8.7988x; 1.0952x over previous
//
#include <hip/hip_runtime.h>
#include <hip/hip_bf16.h>

// Problem constants (hardcoded from setup_inputs):
// B=4, N=4096, C=256, h=8, d=32, H=W=L=16, M=512 (8x8x8), EPS=1e-5
#define SCALE_QK 0.17677669529663687f  // 32^-0.5

// ---------------------------------------------------------------------------
// prep: transpose weights (for coalesced GEMM reads) + zero ssq/sumv
// ---------------------------------------------------------------------------
__global__ __launch_bounds__(256) void prep_kernel(
    const float* __restrict__ pw, const float* __restrict__ kvw,
    const float* __restrict__ pjw,
    float* __restrict__ wtpw, float* __restrict__ wtkv, float* __restrict__ wtpj,
    float* __restrict__ ssq, float* __restrict__ sumv) {
  const int g = blockIdx.x * 256 + threadIdx.x;
  if (g < 65536) {
    const int c = g >> 8, o = g & 255;
    wtpw[g] = pw[o * 256 + c];
  } else if (g < 196608) {
    const int g2 = g - 65536;
    const int c = g2 >> 9, o = g2 & 511;
    wtkv[g2] = kvw[o * 256 + c];
  } else {
    const int g3 = g - 196608;
    const int c = g3 >> 8, o = g3 & 255;
    wtpj[g3] = pjw[o * 256 + c];
  }
  if (g < 512) ssq[g] = 0.0f;                      // 16-way spread x 32
  if (g >= 512 && g < 512 + 1024) sumv[g - 512] = 0.0f;
}

// ---------------------------------------------------------------------------
// depthwise conv3d (3x3x3, stride1, pad1) + BatchNorm (inference) -> qdw[B,N,C]
// ---------------------------------------------------------------------------
__global__ __launch_bounds__(256) void dwbn_kernel(
    const float* __restrict__ x, const float* __restrict__ w,
    const float* __restrict__ wb, const float* __restrict__ bg,
    const float* __restrict__ bb, const float* __restrict__ bm,
    const float* __restrict__ bv, float* __restrict__ outq) {
  const int blk = blockIdx.x;
  const int b = blk >> 12, n = blk & 4095;
  const int i0 = n >> 8, i1 = (n >> 4) & 15, i2 = n & 15;
  const int c = threadIdx.x;
  float acc = wb[c];
#pragma unroll
  for (int k0 = 0; k0 < 3; ++k0) {
    const int z = i0 + k0 - 1;
    if ((unsigned)z >= 16u) continue;
#pragma unroll
    for (int k1 = 0; k1 < 3; ++k1) {
      const int y = i1 + k1 - 1;
      if ((unsigned)y >= 16u) continue;
#pragma unroll
      for (int k2 = 0; k2 < 3; ++k2) {
        const int xx = i2 + k2 - 1;
        if ((unsigned)xx >= 16u) continue;
        acc = fmaf(w[c * 27 + (k0 * 3 + k1) * 3 + k2],
                   x[((b * 4096) + ((z * 16 + y) * 16 + xx)) * 256 + c], acc);
      }
    }
  }
  const float sc = bg[c] * rsqrtf(bv[c] + 1e-5f);
  outq[blk * 256 + c] = (acc - bm[c]) * sc + bb[c];
}

// ---------------------------------------------------------------------------
// strided depthwise conv3d (stride2) + LayerNorm over C -> xsln[B*M, C]
// ---------------------------------------------------------------------------
__global__ __launch_bounds__(256) void srln_kernel(
    const float* __restrict__ x, const float* __restrict__ w,
    const float* __restrict__ wb, const float* __restrict__ lg,
    const float* __restrict__ lb, float* __restrict__ outx) {
  const int blk = blockIdx.x;
  const int b = blk >> 9, m = blk & 511;
  const int o0 = m >> 6, o1 = (m >> 3) & 7, o2 = m & 7;
  const int c = threadIdx.x;
  float acc = wb[c];
#pragma unroll
  for (int k0 = 0; k0 < 3; ++k0) {
    const int z = o0 * 2 + k0 - 1;
    if ((unsigned)z >= 16u) continue;
#pragma unroll
    for (int k1 = 0; k1 < 3; ++k1) {
      const int y = o1 * 2 + k1 - 1;
      if ((unsigned)y >= 16u) continue;
#pragma unroll
      for (int k2 = 0; k2 < 3; ++k2) {
        const int xx = o2 * 2 + k2 - 1;
        if ((unsigned)xx >= 16u) continue;
        acc = fmaf(w[c * 27 + (k0 * 3 + k1) * 3 + k2],
                   x[((b * 4096) + ((z * 16 + y) * 16 + xx)) * 256 + c], acc);
      }
    }
  }
  __shared__ float r1[4], r2[4];
  float s1 = acc, s2 = acc * acc;
#pragma unroll
  for (int off = 32; off >= 1; off >>= 1) {
    s1 += __shfl_xor(s1, off);
    s2 += __shfl_xor(s2, off);
  }
  const int t = threadIdx.x;
  if ((t & 63) == 0) { r1[t >> 6] = s1; r2[t >> 6] = s2; }
  __syncthreads();
  const float mu = (r1[0] + r1[1] + r1[2] + r1[3]) * (1.0f / 256.0f);
  const float ms = (r2[0] + r2[1] + r2[2] + r2[3]) * (1.0f / 256.0f);
  const float rs = rsqrtf(ms - mu * mu + 1e-5f);
  outx[blk * 256 + c] = (acc - mu) * rs * lg[c] + lb[c];
}

// ---------------------------------------------------------------------------
// GEMM: Out[row][c0+cc] = sum_k A[row][k] * Wt[k][c0+cc] (+bias)
// MODE 1: deferred-instance-norm transform on A while staging.
// ---------------------------------------------------------------------------
template <int MODE>
__global__ __launch_bounds__(256) void gemm_kernel(
    const float* __restrict__ A, const float* __restrict__ Wt,
    const float* __restrict__ bias, float* __restrict__ Out, const int ldW,
    const float* __restrict__ sumv, const float* __restrict__ rstd) {
  __shared__ float a_t[32][68];
  __shared__ float w_s[32][260];
  const int t = threadIdx.x;
  const int r0 = blockIdx.x * 64;
  const int c0 = blockIdx.y * 256;
  const int rt = t & 15, ct = t >> 4;
  const int bidx = r0 >> 12;
  const float invM = 1.0f / 512.0f;
  float acc[4][16];
#pragma unroll
  for (int rr = 0; rr < 4; ++rr)
#pragma unroll
    for (int cc = 0; cc < 16; ++cc) acc[rr][cc] = 0.0f;

  for (int k0 = 0; k0 < 256; k0 += 32) {
    {  // stage A^T
      const int kk = t & 31;
      int rl = t >> 5;
#pragma unroll
      for (int p = 0; p < 8; ++p, rl += 8) {
        float v = A[(r0 + rl) * 256 + k0 + kk];
        if (MODE == 1) {
          const int kg = k0 + kk;
          v = (v - invM * sumv[bidx * 256 + kg]) * rstd[bidx * 8 + (kg >> 5)];
        }
        a_t[kk][rl] = v;
      }
    }
    {  // stage W
      const int cq = (t & 63) * 4;
      int kk = t >> 6;
#pragma unroll
      for (int p = 0; p < 8; ++p, kk += 4) {
        const float4 v = *(const float4*)&Wt[(k0 + kk) * ldW + c0 + cq];
        *(float4*)&w_s[kk][cq] = v;
      }
    }
    __syncthreads();
#pragma unroll
    for (int kk = 0; kk < 32; ++kk) {
      const float4 a4 = *(const float4*)&a_t[kk][rt * 4];
      const float av[4] = {a4.x, a4.y, a4.z, a4.w};
      float4 w4[4];
#pragma unroll
      for (int q = 0; q < 4; ++q) w4[q] = *(const float4*)&w_s[kk][ct * 16 + q * 4];
#pragma unroll
      for (int rr = 0; rr < 4; ++rr) {
#pragma unroll
        for (int q = 0; q < 4; ++q) {
          acc[rr][q * 4 + 0] = fmaf(av[rr], w4[q].x, acc[rr][q * 4 + 0]);
          acc[rr][q * 4 + 1] = fmaf(av[rr], w4[q].y, acc[rr][q * 4 + 1]);
          acc[rr][q * 4 + 2] = fmaf(av[rr], w4[q].z, acc[rr][q * 4 + 2]);
          acc[rr][q * 4 + 3] = fmaf(av[rr], w4[q].w, acc[rr][q * 4 + 3]);
        }
      }
    }
    __syncthreads();
  }
#pragma unroll
  for (int rr = 0; rr < 4; ++rr) {
    const int row = r0 + rt * 4 + rr;
#pragma unroll
    for (int q = 0; q < 4; ++q) {
      const int cc = c0 + ct * 16 + q * 4;
      float4 o;
      o.x = acc[rr][q * 4 + 0];
      o.y = acc[rr][q * 4 + 1];
      o.z = acc[rr][q * 4 + 2];
      o.w = acc[rr][q * 4 + 3];
      if (bias != nullptr) {
        o.x += bias[cc + 0]; o.y += bias[cc + 1];
        o.z += bias[cc + 2]; o.w += bias[cc + 3];
      }
      *(float4*)&Out[row * ldW + cc] = o;
    }
  }
}

// ---------------------------------------------------------------------------
// kt: K^T per batch -> ktb[b][k<256][m<512] (coalesced QK reads). LDS tiled.
// ---------------------------------------------------------------------------
__global__ __launch_bounds__(256) void kt_kernel(const float* __restrict__ kvb,
                                                 float* __restrict__ ktb) {
  __shared__ float tile[32][33];
  const int blk = blockIdx.x;  // b(4) x mt(16) x kt8(8)
  const int b = blk >> 7, mt = (blk >> 3) & 15, k8 = blk & 7;
  const int m0 = mt * 32, k0 = k8 * 32;
  const int t = threadIdx.x;
  {
    const int ml = t >> 3, kl = (t & 7) * 4;
    const float4 v = *(const float4*)&kvb[((b * 512 + m0 + ml) * 512) + k0 + kl];
    tile[ml][kl + 0] = v.x; tile[ml][kl + 1] = v.y;
    tile[ml][kl + 2] = v.z; tile[ml][kl + 3] = v.w;
  }
  __syncthreads();
  {
    const int kl = t >> 3, ml = (t & 7) * 4;
    float4 o;
    o.x = tile[ml + 0][kl]; o.y = tile[ml + 1][kl];
    o.z = tile[ml + 2][kl]; o.w = tile[ml + 3][kl];
    *(float4*)&ktb[((b * 256 + k0 + kl) * 512) + m0 + ml] = o;
  }
}

// ---------------------------------------------------------------------------
// sumv[b][c] = sum_m v[b][m][c]
// ---------------------------------------------------------------------------
__global__ __launch_bounds__(256) void sumv_kernel(const float* __restrict__ kvb,
                                                   float* __restrict__ sumv) {
  const int blk = blockIdx.x;
  const int b = blk >> 3, grp = blk & 7;
  const int c = threadIdx.x;
  float s = 0.0f;
  for (int mm = 0; mm < 64; ++mm) {
    const int m = grp * 64 + mm;
    s += kvb[((b * 512 + m) * 512) + 256 + c];
  }
  atomicAdd(&sumv[b * 256 + c], s);
}

__global__ void rstd_kernel(const float* __restrict__ ssq, float* __restrict__ rstd) {
  const int t = threadIdx.x;
  if (t < 32) {
    float s = 0.0f;
#pragma unroll
    for (int sp = 0; sp < 16; ++sp) s += ssq[sp * 32 + t];
    const float e2 = s * (1.0f / (4096.0f * 512.0f));
    const float invM = 1.0f / 512.0f;
    rstd[t] = rsqrtf(e2 - invM * invM + 1e-5f);
  }
}

// ---------------------------------------------------------------------------
// Fused attention v7: block = (b, 8 q-rows), 512 threads = 8 waves.
// Wave = head: QK reads K^T rows ONCE per block; 8-row acc doubles FMAs per
// K load vs v6. Scores/p in 128KB LDS, quad XOR-swizzle (key=row&7=head) so
// PV's 8 m-group b128 reads hit 8 distinct bank-quads (v6's 8-way conflict).
// Mix: wave = q-row, full Wr[8][8] (256-VGPR budget via launch_bounds(512,2)).
// All barriers top-level straight-line (no barrier-loop register indexing).
// ---------------------------------------------------------------------------
__device__ __forceinline__ int pswz(int row, int m) {
  const int q = m >> 2;
  return row * 512 + (((q ^ ((q >> 4) & 7)) << 2) | (m & 3));
}

__global__ __launch_bounds__(512, 2) void attn_kernel(
    const float* __restrict__ qb, const float* __restrict__ ktb,
    const float* __restrict__ kvb, const float* __restrict__ tw,
    float* __restrict__ ssq, float* __restrict__ out_un) {
  __shared__ float P[64 * 512];   // scores then p: row = nn*8 + head (swizzled)
  __shared__ float Qs[8 * 256];   // Qs[row][k], scaled
  __shared__ float sq_lds[8][8];
  const int t = threadIdx.x;
  const int blk = blockIdx.x;
  const int b = blk >> 9;
  const int n0 = (blk & 511) << 3;
  const int w = t >> 6, l = t & 63;

  {  // stage Q row-major, scaled (b128 conflict-free)
    const int row = t >> 6, kq = t & 63;
    const float4 v = *(const float4*)&qb[((b * 4096 + n0 + row) * 256) + kq * 4];
    float4 s;
    s.x = v.x * SCALE_QK; s.y = v.y * SCALE_QK;
    s.z = v.z * SCALE_QK; s.w = v.w * SCALE_QK;
    *(float4*)&Qs[row * 256 + kq * 4] = s;
  }
  __syncthreads();

  // ---------------- QK: wave w = head; lane m = l*2+{0,1} + e*128 -----------
  float acc[8][8];  // [q-row][e*2+s]
#pragma unroll
  for (int r = 0; r < 8; ++r)
#pragma unroll
    for (int e = 0; e < 8; ++e) acc[r][e] = 0.0f;
  {
    const float* ktr = &ktb[(size_t)((b * 256 + w * 32) << 9)];
    const int m2 = l * 2;
#pragma unroll 4
    for (int k = 0; k < 32; ++k) {
      const float2 c0 = *(const float2*)&ktr[(k << 9) + m2];
      const float2 c1 = *(const float2*)&ktr[(k << 9) + 128 + m2];
      const float2 c2 = *(const float2*)&ktr[(k << 9) + 256 + m2];
      const float2 c3 = *(const float2*)&ktr[(k << 9) + 384 + m2];
#pragma unroll
      for (int r = 0; r < 8; ++r) {
        const float qv = Qs[r * 256 + w * 32 + k];  // broadcast
        acc[r][0] = fmaf(qv, c0.x, acc[r][0]); acc[r][1] = fmaf(qv, c0.y, acc[r][1]);
        acc[r][2] = fmaf(qv, c1.x, acc[r][2]); acc[r][3] = fmaf(qv, c1.y, acc[r][3]);
        acc[r][4] = fmaf(qv, c2.x, acc[r][4]); acc[r][5] = fmaf(qv, c2.y, acc[r][5]);
        acc[r][6] = fmaf(qv, c3.x, acc[r][6]); acc[r][7] = fmaf(qv, c3.y, acc[r][7]);
      }
    }
  }
  // write raw scores: row = r*8 + w (swizzled)
#pragma unroll
  for (int r = 0; r < 8; ++r) {
#pragma unroll
    for (int e = 0; e < 4; ++e) {
      float2 s2;
      s2.x = acc[r][e * 2 + 0];
      s2.y = acc[r][e * 2 + 1];
      *(float2*)&P[pswz(r * 8 + w, e * 128 + l * 2)] = s2;
    }
  }
  __syncthreads();

  // ---------------- mix: wave = q-row w, full 8x8 Wr ----------------
  float mixed[8][8];  // [out-head i][e*2+s]
  {
    float Wr[8][8];
#pragma unroll
    for (int i = 0; i < 8; ++i)
#pragma unroll
      for (int jj = 0; jj < 8; ++jj) Wr[i][jj] = tw[i * 8 + jj];
#pragma unroll
    for (int i = 0; i < 8; ++i)
#pragma unroll
      for (int e = 0; e < 8; ++e) mixed[i][e] = 0.0f;  // tb dropped: softmax-invariant
#pragma unroll
    for (int jj = 0; jj < 8; ++jj) {
#pragma unroll
      for (int e = 0; e < 4; ++e) {
        const float2 r2 = *(const float2*)&P[pswz(w * 8 + jj, e * 128 + l * 2)];
#pragma unroll
        for (int i = 0; i < 8; ++i) {
          mixed[i][e * 2 + 0] = fmaf(Wr[i][jj], r2.x, mixed[i][e * 2 + 0]);
          mixed[i][e * 2 + 1] = fmaf(Wr[i][jj], r2.y, mixed[i][e * 2 + 1]);
        }
      }
    }
  }
  __syncthreads();  // all mix reads done before p overwrites scores

  // ---------------- softmax per (row w, head i) in regs ----------------
#pragma unroll
  for (int i = 0; i < 8; ++i) {
    float mx = mixed[i][0];
#pragma unroll
    for (int e = 1; e < 8; ++e) mx = fmaxf(mx, mixed[i][e]);
#pragma unroll
    for (int off = 32; off >= 1; off >>= 1) mx = fmaxf(mx, __shfl_xor(mx, off));
    float s = 0.0f;
#pragma unroll
    for (int e = 0; e < 8; ++e) {
      const float ev = __expf(mixed[i][e] - mx);
      mixed[i][e] = ev;
      s += ev;
    }
#pragma unroll
    for (int off = 32; off >= 1; off >>= 1) s += __shfl_xor(s, off);
    const float rinv = 1.0f / s;
    float sq = 0.0f;
#pragma unroll
    for (int e = 0; e < 4; ++e) {
      float2 pv;
      pv.x = mixed[i][e * 2 + 0] * rinv;
      pv.y = mixed[i][e * 2 + 1] * rinv;
      sq = fmaf(pv.x, pv.x, sq);
      sq = fmaf(pv.y, pv.y, sq);
      *(float2*)&P[pswz(w * 8 + i, e * 128 + l * 2)] = pv;
    }
#pragma unroll
    for (int off = 32; off >= 1; off >>= 1) sq += __shfl_xor(sq, off);
    if (l == 0) sq_lds[w][i] = sq;
  }
  __syncthreads();

  if (t < 8) {
    float s8 = 0.0f;
#pragma unroll
    for (int r = 0; r < 8; ++r) s8 += sq_lds[r][t];
    atomicAdd(&ssq[(blk & 15) * 32 + b * 8 + t], s8);
  }

  // ---------------- PV: wave w = head; lane (mgrp=l>>3, d=l&7) --------------
  {
    float av[8][4];  // [q-row][d-comp]
#pragma unroll
    for (int r = 0; r < 8; ++r)
#pragma unroll
      for (int e = 0; e < 4; ++e) av[r][e] = 0.0f;
    const int mbase = (l >> 3) * 64;
    const int vcol = 256 + w * 32 + (l & 7) * 4;
#pragma unroll 2
    for (int mq = 0; mq < 16; ++mq) {
      const int m0 = mbase + mq * 4;
      float4 p4[8];
#pragma unroll
      for (int r = 0; r < 8; ++r)
        p4[r] = *(const float4*)&P[pswz(r * 8 + w, m0)];
#pragma unroll
      for (int e = 0; e < 4; ++e) {
        const float4 v4 = *(const float4*)&kvb[((b * 512 + m0 + e) * 512) + vcol];
#pragma unroll
        for (int r = 0; r < 8; ++r) {
          const float p = (&p4[r].x)[e];
          av[r][0] = fmaf(p, v4.x, av[r][0]);
          av[r][1] = fmaf(p, v4.y, av[r][1]);
          av[r][2] = fmaf(p, v4.z, av[r][2]);
          av[r][3] = fmaf(p, v4.w, av[r][3]);
        }
      }
    }
    // reduce across the 8 m-groups (lanes differing in bits 3..5)
#pragma unroll
    for (int r = 0; r < 8; ++r) {
#pragma unroll
      for (int e = 0; e < 4; ++e) {
        float v = av[r][e];
        v += __shfl_xor(v, 8);
        v += __shfl_xor(v, 16);
        v += __shfl_xor(v, 32);
        av[r][e] = v;
      }
    }
    if (l < 8) {
#pragma unroll
      for (int r = 0; r < 8; ++r) {
        float4 o;
        o.x = av[r][0]; o.y = av[r][1]; o.z = av[r][2]; o.w = av[r][3];
        *(float4*)&out_un[((b * 4096) + n0 + r) * 256 + w * 32 + l * 4] = o;
      }
    }
  }
}

// ---------------------------------------------------------------------------
extern "C" void kernel_launch(void* const* d_in, const int* in_sizes, int n_in,
                              void* d_out, int out_size, void* d_ws, size_t ws_size,
                              hipStream_t stream) {
  const float* x   = (const float*)d_in[0];
  const float* qdww= (const float*)d_in[1];
  const float* qdwb= (const float*)d_in[2];
  const float* bng = (const float*)d_in[3];
  const float* bnb = (const float*)d_in[4];
  const float* bnm = (const float*)d_in[5];
  const float* bnv = (const float*)d_in[6];
  const float* pw  = (const float*)d_in[7];
  const float* pwb = (const float*)d_in[8];
  const float* srw = (const float*)d_in[9];
  const float* srb = (const float*)d_in[10];
  const float* lng = (const float*)d_in[11];
  const float* lnb = (const float*)d_in[12];
  const float* kvw = (const float*)d_in[13];
  const float* tw  = (const float*)d_in[14];
  // d_in[15] = trans_b: softmax-invariant, unused
  const float* pjw = (const float*)d_in[16];
  const float* pjb = (const float*)d_in[17];
  float* out = (float*)d_out;
  float* ws = (float*)d_ws;

  float* qdw   = ws + 0;          // 4,194,304
  float* qbuf  = ws + 4194304;    // 4,194,304
  float* xsln  = ws + 8388608;    //   524,288
  float* kvb   = ws + 8912896;    // 1,048,576
  float* ktb   = ws + 9961472;    //   524,288
  float* wtpw  = ws + 10485760;   //    65,536
  float* wtkv  = ws + 10551296;   //   131,072
  float* wtpj  = ws + 10682368;   //    65,536
  float* sumvp = ws + 10747904;   //     1,024
  float* ssqp  = ws + 10748928;   //       512
  float* rstdp = ws + 10749440;   //        32

  prep_kernel<<<1024, 256, 0, stream>>>(pw, kvw, pjw, wtpw, wtkv, wtpj, ssqp, sumvp);
  dwbn_kernel<<<16384, 256, 0, stream>>>(x, qdww, qdwb, bng, bnb, bnm, bnv, qdw);
  gemm_kernel<0><<<dim3(256, 1), 256, 0, stream>>>(qdw, wtpw, pwb, qbuf, 256, nullptr, nullptr);
  srln_kernel<<<2048, 256, 0, stream>>>(x, srw, srb, lng, lnb, xsln);
  gemm_kernel<0><<<dim3(32, 2), 256, 0, stream>>>(xsln, wtkv, nullptr, kvb, 512, nullptr, nullptr);
  kt_kernel<<<512, 256, 0, stream>>>(kvb, ktb);
  sumv_kernel<<<32, 256, 0, stream>>>(kvb, sumvp);
  attn_kernel<<<2048, 512, 0, stream>>>(qbuf, ktb, kvb, tw, ssqp, out);
  rstd_kernel<<<1, 64, 0, stream>>>(ssqp, rstdp);
  gemm_kernel<1><<<dim3(256, 1), 256, 0, stream>>>(out, wtpj, pjb, out, 256, sumvp, rstdp);
}

// Round 10
// 470.562 us; speedup vs baseline: 9.4361x; 1.0724x over previous
//
#include <hip/hip_runtime.h>
#include <hip/hip_bf16.h>

// Problem constants: B=4, N=4096, C=256, h=8, d=32, M=512, EPS=1e-5
#define SCALE_QK 0.17677669529663687f  // 32^-0.5

// ---------------------------------------------------------------------------
// prep: transpose weights + zero ssq/sumv
// ---------------------------------------------------------------------------
__global__ __launch_bounds__(256) void prep_kernel(
    const float* __restrict__ pw, const float* __restrict__ kvw,
    const float* __restrict__ pjw,
    float* __restrict__ wtpw, float* __restrict__ wtkv, float* __restrict__ wtpj,
    float* __restrict__ ssq, float* __restrict__ sumv) {
  const int g = blockIdx.x * 256 + threadIdx.x;
  if (g < 65536) {
    const int c = g >> 8, o = g & 255;
    wtpw[g] = pw[o * 256 + c];
  } else if (g < 196608) {
    const int g2 = g - 65536;
    const int c = g2 >> 9, o = g2 & 511;
    wtkv[g2] = kvw[o * 256 + c];
  } else {
    const int g3 = g - 196608;
    const int c = g3 >> 8, o = g3 & 255;
    wtpj[g3] = pjw[o * 256 + c];
  }
  if (g < 512) ssq[g] = 0.0f;
  if (g >= 512 && g < 512 + 1024) sumv[g - 512] = 0.0f;
}

// ---------------------------------------------------------------------------
// depthwise conv3d + BatchNorm -> qdw[B,N,C]
// ---------------------------------------------------------------------------
__global__ __launch_bounds__(256) void dwbn_kernel(
    const float* __restrict__ x, const float* __restrict__ w,
    const float* __restrict__ wb, const float* __restrict__ bg,
    const float* __restrict__ bb, const float* __restrict__ bm,
    const float* __restrict__ bv, float* __restrict__ outq) {
  const int blk = blockIdx.x;
  const int b = blk >> 12, n = blk & 4095;
  const int i0 = n >> 8, i1 = (n >> 4) & 15, i2 = n & 15;
  const int c = threadIdx.x;
  float acc = wb[c];
#pragma unroll
  for (int k0 = 0; k0 < 3; ++k0) {
    const int z = i0 + k0 - 1;
    if ((unsigned)z >= 16u) continue;
#pragma unroll
    for (int k1 = 0; k1 < 3; ++k1) {
      const int y = i1 + k1 - 1;
      if ((unsigned)y >= 16u) continue;
#pragma unroll
      for (int k2 = 0; k2 < 3; ++k2) {
        const int xx = i2 + k2 - 1;
        if ((unsigned)xx >= 16u) continue;
        acc = fmaf(w[c * 27 + (k0 * 3 + k1) * 3 + k2],
                   x[((b * 4096) + ((z * 16 + y) * 16 + xx)) * 256 + c], acc);
      }
    }
  }
  const float sc = bg[c] * rsqrtf(bv[c] + 1e-5f);
  outq[blk * 256 + c] = (acc - bm[c]) * sc + bb[c];
}

// ---------------------------------------------------------------------------
// strided depthwise conv3d + LayerNorm -> xsln[B*M, C]
// ---------------------------------------------------------------------------
__global__ __launch_bounds__(256) void srln_kernel(
    const float* __restrict__ x, const float* __restrict__ w,
    const float* __restrict__ wb, const float* __restrict__ lg,
    const float* __restrict__ lb, float* __restrict__ outx) {
  const int blk = blockIdx.x;
  const int b = blk >> 9, m = blk & 511;
  const int o0 = m >> 6, o1 = (m >> 3) & 7, o2 = m & 7;
  const int c = threadIdx.x;
  float acc = wb[c];
#pragma unroll
  for (int k0 = 0; k0 < 3; ++k0) {
    const int z = o0 * 2 + k0 - 1;
    if ((unsigned)z >= 16u) continue;
#pragma unroll
    for (int k1 = 0; k1 < 3; ++k1) {
      const int y = o1 * 2 + k1 - 1;
      if ((unsigned)y >= 16u) continue;
#pragma unroll
      for (int k2 = 0; k2 < 3; ++k2) {
        const int xx = o2 * 2 + k2 - 1;
        if ((unsigned)xx >= 16u) continue;
        acc = fmaf(w[c * 27 + (k0 * 3 + k1) * 3 + k2],
                   x[((b * 4096) + ((z * 16 + y) * 16 + xx)) * 256 + c], acc);
      }
    }
  }
  __shared__ float r1[4], r2[4];
  float s1 = acc, s2 = acc * acc;
#pragma unroll
  for (int off = 32; off >= 1; off >>= 1) {
    s1 += __shfl_xor(s1, off);
    s2 += __shfl_xor(s2, off);
  }
  const int t = threadIdx.x;
  if ((t & 63) == 0) { r1[t >> 6] = s1; r2[t >> 6] = s2; }
  __syncthreads();
  const float mu = (r1[0] + r1[1] + r1[2] + r1[3]) * (1.0f / 256.0f);
  const float ms = (r2[0] + r2[1] + r2[2] + r2[3]) * (1.0f / 256.0f);
  const float rs = rsqrtf(ms - mu * mu + 1e-5f);
  outx[blk * 256 + c] = (acc - mu) * rs * lg[c] + lb[c];
}

// ---------------------------------------------------------------------------
// GEMM v2: 64 rows x 128 cols per block (2 blocks/CU). acc[4][8].
// MODE 1: deferred-instance-norm transform on A while staging.
// ---------------------------------------------------------------------------
template <int MODE>
__global__ __launch_bounds__(256) void gemm_kernel(
    const float* __restrict__ A, const float* __restrict__ Wt,
    const float* __restrict__ bias, float* __restrict__ Out, const int ldW,
    const float* __restrict__ sumv, const float* __restrict__ rstd) {
  __shared__ float a_t[32][68];
  __shared__ float w_s[32][132];
  const int t = threadIdx.x;
  const int r0 = blockIdx.x * 64;
  const int c0 = blockIdx.y * 128;
  const int rt = t & 15, ct = t >> 4;
  const int bidx = r0 >> 12;
  const float invM = 1.0f / 512.0f;
  float acc[4][8];
#pragma unroll
  for (int rr = 0; rr < 4; ++rr)
#pragma unroll
    for (int cc = 0; cc < 8; ++cc) acc[rr][cc] = 0.0f;

  for (int k0 = 0; k0 < 256; k0 += 32) {
    {  // stage A^T
      const int kk = t & 31;
      int rl = t >> 5;
#pragma unroll
      for (int p = 0; p < 8; ++p, rl += 8) {
        float v = A[(r0 + rl) * 256 + k0 + kk];
        if (MODE == 1) {
          const int kg = k0 + kk;
          v = (v - invM * sumv[bidx * 256 + kg]) * rstd[bidx * 8 + (kg >> 5)];
        }
        a_t[kk][rl] = v;
      }
    }
    {  // stage W (32k x 128 cols)
      const int cq = (t & 31) * 4;
      int kk = t >> 5;
#pragma unroll
      for (int p = 0; p < 4; ++p, kk += 8) {
        const float4 v = *(const float4*)&Wt[(k0 + kk) * ldW + c0 + cq];
        *(float4*)&w_s[kk][cq] = v;
      }
    }
    __syncthreads();
#pragma unroll
    for (int kk = 0; kk < 32; ++kk) {
      const float4 a4 = *(const float4*)&a_t[kk][rt * 4];
      const float av[4] = {a4.x, a4.y, a4.z, a4.w};
      float4 w4[2];
#pragma unroll
      for (int q = 0; q < 2; ++q) w4[q] = *(const float4*)&w_s[kk][ct * 8 + q * 4];
#pragma unroll
      for (int rr = 0; rr < 4; ++rr) {
#pragma unroll
        for (int q = 0; q < 2; ++q) {
          acc[rr][q * 4 + 0] = fmaf(av[rr], w4[q].x, acc[rr][q * 4 + 0]);
          acc[rr][q * 4 + 1] = fmaf(av[rr], w4[q].y, acc[rr][q * 4 + 1]);
          acc[rr][q * 4 + 2] = fmaf(av[rr], w4[q].z, acc[rr][q * 4 + 2]);
          acc[rr][q * 4 + 3] = fmaf(av[rr], w4[q].w, acc[rr][q * 4 + 3]);
        }
      }
    }
    __syncthreads();
  }
#pragma unroll
  for (int rr = 0; rr < 4; ++rr) {
    const int row = r0 + rt * 4 + rr;
#pragma unroll
    for (int q = 0; q < 2; ++q) {
      const int cc = c0 + ct * 8 + q * 4;
      float4 o;
      o.x = acc[rr][q * 4 + 0];
      o.y = acc[rr][q * 4 + 1];
      o.z = acc[rr][q * 4 + 2];
      o.w = acc[rr][q * 4 + 3];
      if (bias != nullptr) {
        o.x += bias[cc + 0]; o.y += bias[cc + 1];
        o.z += bias[cc + 2]; o.w += bias[cc + 3];
      }
      *(float4*)&Out[row * ldW + cc] = o;
    }
  }
}

// ---------------------------------------------------------------------------
// kt: K^T per batch -> ktb[b][k][m]
// ---------------------------------------------------------------------------
__global__ __launch_bounds__(256) void kt_kernel(const float* __restrict__ kvb,
                                                 float* __restrict__ ktb) {
  __shared__ float tile[32][33];
  const int blk = blockIdx.x;
  const int b = blk >> 7, mt = (blk >> 3) & 15, k8 = blk & 7;
  const int m0 = mt * 32, k0 = k8 * 32;
  const int t = threadIdx.x;
  {
    const int ml = t >> 3, kl = (t & 7) * 4;
    const float4 v = *(const float4*)&kvb[((b * 512 + m0 + ml) * 512) + k0 + kl];
    tile[ml][kl + 0] = v.x; tile[ml][kl + 1] = v.y;
    tile[ml][kl + 2] = v.z; tile[ml][kl + 3] = v.w;
  }
  __syncthreads();
  {
    const int kl = t >> 3, ml = (t & 7) * 4;
    float4 o;
    o.x = tile[ml + 0][kl]; o.y = tile[ml + 1][kl];
    o.z = tile[ml + 2][kl]; o.w = tile[ml + 3][kl];
    *(float4*)&ktb[((b * 256 + k0 + kl) * 512) + m0 + ml] = o;
  }
}

// ---------------------------------------------------------------------------
// sumv[b][c] = sum_m v[b][m][c]
// ---------------------------------------------------------------------------
__global__ __launch_bounds__(256) void sumv_kernel(const float* __restrict__ kvb,
                                                   float* __restrict__ sumv) {
  const int blk = blockIdx.x;
  const int b = blk >> 3, grp = blk & 7;
  const int c = threadIdx.x;
  float s = 0.0f;
  for (int mm = 0; mm < 64; ++mm) {
    const int m = grp * 64 + mm;
    s += kvb[((b * 512 + m) * 512) + 256 + c];
  }
  atomicAdd(&sumv[b * 256 + c], s);
}

__global__ void rstd_kernel(const float* __restrict__ ssq, float* __restrict__ rstd) {
  const int t = threadIdx.x;
  if (t < 32) {
    float s = 0.0f;
#pragma unroll
    for (int sp = 0; sp < 16; ++sp) s += ssq[sp * 32 + t];
    const float e2 = s * (1.0f / (4096.0f * 512.0f));
    const float invM = 1.0f / 512.0f;
    rstd[t] = rsqrtf(e2 - invM * invM + 1e-5f);
  }
}

// ---------------------------------------------------------------------------
// Fused attention v8: block = (b, 8 q-rows), 512 threads, LDS ~72KB -> 2/CU.
// QK as v7 (wave=head, K read once). Scores through 64KB buffer in TWO
// m-halves (write e01/mix-A/write e23/mix-B; Wr lives in SGPRs so the live
// acc-half fits). Softmax in regs. PV in TWO head-group passes: p = 32 rows
// x 512 (64KB, swizzle key (q>>3)&7), wave=(head-in-group, m-half), LDS
// partial combine. All passes straight-line (no barrier-loop reg indexing).
// ---------------------------------------------------------------------------
__device__ __forceinline__ int pswz2(int row, int m) {
  const int q = m >> 2;
  const int qs = q ^ ((q >> 3) & 7);
  return row * 512 + (qs << 2) + (m & 3);
}

__global__ __launch_bounds__(512, 4) void attn_kernel(
    const float* __restrict__ qb, const float* __restrict__ ktb,
    const float* __restrict__ kvb, const float* __restrict__ tw,
    float* __restrict__ ssq, float* __restrict__ out_un) {
  __shared__ float P[16384];      // 64KB: scores (64 rows x 256) / p (32 x 512)
  __shared__ float Qs[8 * 256];   // 8KB
  __shared__ float sq_lds[8][8];
  const int t = threadIdx.x;
  const int blk = blockIdx.x;
  const int b = blk >> 9;
  const int n0 = (blk & 511) << 3;
  const int w = t >> 6, l = t & 63;

  {  // stage Q row-major, scaled
    const int row = t >> 6, kq = t & 63;
    const float4 v = *(const float4*)&qb[((b * 4096 + n0 + row) * 256) + kq * 4];
    float4 s;
    s.x = v.x * SCALE_QK; s.y = v.y * SCALE_QK;
    s.z = v.z * SCALE_QK; s.w = v.w * SCALE_QK;
    *(float4*)&Qs[row * 256 + kq * 4] = s;
  }
  __syncthreads();

  // ---------------- QK: wave w = head; lane m = l*2+{0,1} + e*128 -----------
  float acc[8][8];
#pragma unroll
  for (int r = 0; r < 8; ++r)
#pragma unroll
    for (int e = 0; e < 8; ++e) acc[r][e] = 0.0f;
  {
    const float* ktr = &ktb[(size_t)((b * 256 + w * 32) << 9)];
    const int m2 = l * 2;
#pragma unroll 4
    for (int k = 0; k < 32; ++k) {
      const float2 c0 = *(const float2*)&ktr[(k << 9) + m2];
      const float2 c1 = *(const float2*)&ktr[(k << 9) + 128 + m2];
      const float2 c2 = *(const float2*)&ktr[(k << 9) + 256 + m2];
      const float2 c3 = *(const float2*)&ktr[(k << 9) + 384 + m2];
#pragma unroll
      for (int r = 0; r < 8; ++r) {
        const float qv = Qs[r * 256 + w * 32 + k];
        acc[r][0] = fmaf(qv, c0.x, acc[r][0]); acc[r][1] = fmaf(qv, c0.y, acc[r][1]);
        acc[r][2] = fmaf(qv, c1.x, acc[r][2]); acc[r][3] = fmaf(qv, c1.y, acc[r][3]);
        acc[r][4] = fmaf(qv, c2.x, acc[r][4]); acc[r][5] = fmaf(qv, c2.y, acc[r][5]);
        acc[r][6] = fmaf(qv, c3.x, acc[r][6]); acc[r][7] = fmaf(qv, c3.y, acc[r][7]);
      }
    }
  }

  float Wr[8][8];  // uniform -> SGPRs
#pragma unroll
  for (int i = 0; i < 8; ++i)
#pragma unroll
    for (int jj = 0; jj < 8; ++jj) Wr[i][jj] = tw[i * 8 + jj];

  float mixed[8][8];
#pragma unroll
  for (int i = 0; i < 8; ++i)
#pragma unroll
    for (int e = 0; e < 8; ++e) mixed[i][e] = 0.0f;  // tb dropped: softmax-invariant

  // ---- scores half A (m<256): write e=0,1 ----
#pragma unroll
  for (int r = 0; r < 8; ++r) {
    float2 s0; s0.x = acc[r][0]; s0.y = acc[r][1];
    float2 s1; s1.x = acc[r][2]; s1.y = acc[r][3];
    *(float2*)&P[(r * 8 + w) * 256 + l * 2] = s0;
    *(float2*)&P[(r * 8 + w) * 256 + 128 + l * 2] = s1;
  }
  __syncthreads();
  // ---- mix half A: wave = q-row w ----
#pragma unroll
  for (int jj = 0; jj < 8; ++jj) {
    const float2 ra = *(const float2*)&P[(w * 8 + jj) * 256 + l * 2];
    const float2 rb = *(const float2*)&P[(w * 8 + jj) * 256 + 128 + l * 2];
#pragma unroll
    for (int i = 0; i < 8; ++i) {
      mixed[i][0] = fmaf(Wr[i][jj], ra.x, mixed[i][0]);
      mixed[i][1] = fmaf(Wr[i][jj], ra.y, mixed[i][1]);
      mixed[i][2] = fmaf(Wr[i][jj], rb.x, mixed[i][2]);
      mixed[i][3] = fmaf(Wr[i][jj], rb.y, mixed[i][3]);
    }
  }
  __syncthreads();
  // ---- scores half B (m>=256): write e=2,3 ----
#pragma unroll
  for (int r = 0; r < 8; ++r) {
    float2 s0; s0.x = acc[r][4]; s0.y = acc[r][5];
    float2 s1; s1.x = acc[r][6]; s1.y = acc[r][7];
    *(float2*)&P[(r * 8 + w) * 256 + l * 2] = s0;
    *(float2*)&P[(r * 8 + w) * 256 + 128 + l * 2] = s1;
  }
  __syncthreads();
  // ---- mix half B ----
#pragma unroll
  for (int jj = 0; jj < 8; ++jj) {
    const float2 ra = *(const float2*)&P[(w * 8 + jj) * 256 + l * 2];
    const float2 rb = *(const float2*)&P[(w * 8 + jj) * 256 + 128 + l * 2];
#pragma unroll
    for (int i = 0; i < 8; ++i) {
      mixed[i][4] = fmaf(Wr[i][jj], ra.x, mixed[i][4]);
      mixed[i][5] = fmaf(Wr[i][jj], ra.y, mixed[i][5]);
      mixed[i][6] = fmaf(Wr[i][jj], rb.x, mixed[i][6]);
      mixed[i][7] = fmaf(Wr[i][jj], rb.y, mixed[i][7]);
    }
  }
  __syncthreads();

  // ---------------- softmax per (row w, head i); p kept in mixed ------------
#pragma unroll
  for (int i = 0; i < 8; ++i) {
    float mx = mixed[i][0];
#pragma unroll
    for (int e = 1; e < 8; ++e) mx = fmaxf(mx, mixed[i][e]);
#pragma unroll
    for (int off = 32; off >= 1; off >>= 1) mx = fmaxf(mx, __shfl_xor(mx, off));
    float s = 0.0f;
#pragma unroll
    for (int e = 0; e < 8; ++e) {
      const float ev = __expf(mixed[i][e] - mx);
      mixed[i][e] = ev;
      s += ev;
    }
#pragma unroll
    for (int off = 32; off >= 1; off >>= 1) s += __shfl_xor(s, off);
    const float rinv = 1.0f / s;
    float sq = 0.0f;
#pragma unroll
    for (int e = 0; e < 8; ++e) {
      const float p = mixed[i][e] * rinv;
      mixed[i][e] = p;
      sq = fmaf(p, p, sq);
    }
#pragma unroll
    for (int off = 32; off >= 1; off >>= 1) sq += __shfl_xor(sq, off);
    if (l == 0) sq_lds[w][i] = sq;
  }
  __syncthreads();
  if (t < 8) {
    float s8 = 0.0f;
#pragma unroll
    for (int r = 0; r < 8; ++r) s8 += sq_lds[r][t];
    atomicAdd(&ssq[(blk & 15) * 32 + b * 8 + t], s8);
  }

  const int il = w & 3, mh = w >> 2;
  const int mgrp = l >> 3, dl = l & 7;

  // ================= PASS 0: heads 0..3 =================
#pragma unroll
  for (int i = 0; i < 4; ++i) {
#pragma unroll
    for (int e = 0; e < 4; ++e) {
      float2 pv;
      pv.x = mixed[i][e * 2 + 0];
      pv.y = mixed[i][e * 2 + 1];
      *(float2*)&P[pswz2(w * 4 + i, e * 128 + l * 2)] = pv;
    }
  }
  __syncthreads();
  {
    float av[8][4];
#pragma unroll
    for (int r = 0; r < 8; ++r)
#pragma unroll
      for (int e = 0; e < 4; ++e) av[r][e] = 0.0f;
    const int mb = mh * 256 + mgrp * 32;
    const int vcol = 256 + il * 32 + dl * 4;
#pragma unroll 2
    for (int mq = 0; mq < 8; ++mq) {
      const int m0 = mb + mq * 4;
      float4 p4[8];
#pragma unroll
      for (int r = 0; r < 8; ++r) p4[r] = *(const float4*)&P[pswz2(r * 4 + il, m0)];
#pragma unroll
      for (int e = 0; e < 4; ++e) {
        const float4 v4 = *(const float4*)&kvb[((b * 512 + m0 + e) * 512) + vcol];
#pragma unroll
        for (int r = 0; r < 8; ++r) {
          const float p = (&p4[r].x)[e];
          av[r][0] = fmaf(p, v4.x, av[r][0]);
          av[r][1] = fmaf(p, v4.y, av[r][1]);
          av[r][2] = fmaf(p, v4.z, av[r][2]);
          av[r][3] = fmaf(p, v4.w, av[r][3]);
        }
      }
    }
#pragma unroll
    for (int r = 0; r < 8; ++r)
#pragma unroll
      for (int e = 0; e < 4; ++e) {
        float v = av[r][e];
        v += __shfl_xor(v, 8);
        v += __shfl_xor(v, 16);
        v += __shfl_xor(v, 32);
        av[r][e] = v;
      }
    __syncthreads();  // p reads done
    if (l < 8) {
#pragma unroll
      for (int r = 0; r < 8; ++r) {
        float4 o;
        o.x = av[r][0]; o.y = av[r][1]; o.z = av[r][2]; o.w = av[r][3];
        *(float4*)&P[w * 256 + r * 32 + dl * 4] = o;
      }
    }
  }
  __syncthreads();
#pragma unroll
  for (int rep = 0; rep < 2; ++rep) {
    const int idx = rep * 512 + t;
    const int il2 = idx >> 8, r2i = (idx >> 5) & 7, dd = idx & 31;
    const float s = P[il2 * 256 + r2i * 32 + dd] + P[(il2 + 4) * 256 + r2i * 32 + dd];
    out_un[((b * 4096) + n0 + r2i) * 256 + il2 * 32 + dd] = s;
  }
  __syncthreads();

  // ================= PASS 1: heads 4..7 =================
#pragma unroll
  for (int i = 0; i < 4; ++i) {
#pragma unroll
    for (int e = 0; e < 4; ++e) {
      float2 pv;
      pv.x = mixed[4 + i][e * 2 + 0];
      pv.y = mixed[4 + i][e * 2 + 1];
      *(float2*)&P[pswz2(w * 4 + i, e * 128 + l * 2)] = pv;
    }
  }
  __syncthreads();
  {
    float av[8][4];
#pragma unroll
    for (int r = 0; r < 8; ++r)
#pragma unroll
      for (int e = 0; e < 4; ++e) av[r][e] = 0.0f;
    const int mb = mh * 256 + mgrp * 32;
    const int vcol = 256 + (4 + il) * 32 + dl * 4;
#pragma unroll 2
    for (int mq = 0; mq < 8; ++mq) {
      const int m0 = mb + mq * 4;
      float4 p4[8];
#pragma unroll
      for (int r = 0; r < 8; ++r) p4[r] = *(const float4*)&P[pswz2(r * 4 + il, m0)];
#pragma unroll
      for (int e = 0; e < 4; ++e) {
        const float4 v4 = *(const float4*)&kvb[((b * 512 + m0 + e) * 512) + vcol];
#pragma unroll
        for (int r = 0; r < 8; ++r) {
          const float p = (&p4[r].x)[e];
          av[r][0] = fmaf(p, v4.x, av[r][0]);
          av[r][1] = fmaf(p, v4.y, av[r][1]);
          av[r][2] = fmaf(p, v4.z, av[r][2]);
          av[r][3] = fmaf(p, v4.w, av[r][3]);
        }
      }
    }
#pragma unroll
    for (int r = 0; r < 8; ++r)
#pragma unroll
      for (int e = 0; e < 4; ++e) {
        float v = av[r][e];
        v += __shfl_xor(v, 8);
        v += __shfl_xor(v, 16);
        v += __shfl_xor(v, 32);
        av[r][e] = v;
      }
    __syncthreads();  // p reads done
    if (l < 8) {
#pragma unroll
      for (int r = 0; r < 8; ++r) {
        float4 o;
        o.x = av[r][0]; o.y = av[r][1]; o.z = av[r][2]; o.w = av[r][3];
        *(float4*)&P[w * 256 + r * 32 + dl * 4] = o;
      }
    }
  }
  __syncthreads();
#pragma unroll
  for (int rep = 0; rep < 2; ++rep) {
    const int idx = rep * 512 + t;
    const int il2 = idx >> 8, r2i = (idx >> 5) & 7, dd = idx & 31;
    const float s = P[il2 * 256 + r2i * 32 + dd] + P[(il2 + 4) * 256 + r2i * 32 + dd];
    out_un[((b * 4096) + n0 + r2i) * 256 + (4 + il2) * 32 + dd] = s;
  }
}

// ---------------------------------------------------------------------------
extern "C" void kernel_launch(void* const* d_in, const int* in_sizes, int n_in,
                              void* d_out, int out_size, void* d_ws, size_t ws_size,
                              hipStream_t stream) {
  const float* x   = (const float*)d_in[0];
  const float* qdww= (const float*)d_in[1];
  const float* qdwb= (const float*)d_in[2];
  const float* bng = (const float*)d_in[3];
  const float* bnb = (const float*)d_in[4];
  const float* bnm = (const float*)d_in[5];
  const float* bnv = (const float*)d_in[6];
  const float* pw  = (const float*)d_in[7];
  const float* pwb = (const float*)d_in[8];
  const float* srw = (const float*)d_in[9];
  const float* srb = (const float*)d_in[10];
  const float* lng = (const float*)d_in[11];
  const float* lnb = (const float*)d_in[12];
  const float* kvw = (const float*)d_in[13];
  const float* tw  = (const float*)d_in[14];
  // d_in[15] = trans_b: softmax-invariant, unused
  const float* pjw = (const float*)d_in[16];
  const float* pjb = (const float*)d_in[17];
  float* out = (float*)d_out;
  float* ws = (float*)d_ws;

  float* qdw   = ws + 0;          // 4,194,304
  float* qbuf  = ws + 4194304;    // 4,194,304
  float* xsln  = ws + 8388608;    //   524,288
  float* kvb   = ws + 8912896;    // 1,048,576
  float* ktb   = ws + 9961472;    //   524,288
  float* wtpw  = ws + 10485760;   //    65,536
  float* wtkv  = ws + 10551296;   //   131,072
  float* wtpj  = ws + 10682368;   //    65,536
  float* sumvp = ws + 10747904;   //     1,024
  float* ssqp  = ws + 10748928;   //       512
  float* rstdp = ws + 10749440;   //        32

  prep_kernel<<<1024, 256, 0, stream>>>(pw, kvw, pjw, wtpw, wtkv, wtpj, ssqp, sumvp);
  dwbn_kernel<<<16384, 256, 0, stream>>>(x, qdww, qdwb, bng, bnb, bnm, bnv, qdw);
  gemm_kernel<0><<<dim3(256, 2), 256, 0, stream>>>(qdw, wtpw, pwb, qbuf, 256, nullptr, nullptr);
  srln_kernel<<<2048, 256, 0, stream>>>(x, srw, srb, lng, lnb, xsln);
  gemm_kernel<0><<<dim3(32, 4), 256, 0, stream>>>(xsln, wtkv, nullptr, kvb, 512, nullptr, nullptr);
  kt_kernel<<<512, 256, 0, stream>>>(kvb, ktb);
  sumv_kernel<<<32, 256, 0, stream>>>(kvb, sumvp);
  attn_kernel<<<2048, 512, 0, stream>>>(qbuf, ktb, kvb, tw, ssqp, out);
  rstd_kernel<<<1, 64, 0, stream>>>(ssqp, rstdp);
  gemm_kernel<1><<<dim3(256, 2), 256, 0, stream>>>(out, wtpj, pjb, out, 256, sumvp, rstdp);
}